// Round 4
// baseline (2456.449 us; speedup 1.0000x reference)
//
#include <hip/hip_runtime.h>

typedef unsigned short u16;
typedef unsigned int u32;
typedef unsigned long long u64;
typedef short v8s __attribute__((ext_vector_type(8)));
typedef float v4f __attribute__((ext_vector_type(4)));

#define NN 4096
#define BATCH 32

__device__ __forceinline__ float b2f(u16 u) {
  union { u32 i; float f; } c; c.i = ((u32)u) << 16; return c.f;
}
__device__ __forceinline__ u16 f2b(float f) {
  union { float f; u32 i; } c; c.f = f;
  u32 x = c.i;
  return (u16)((x + 0x7fffu + ((x >> 16) & 1u)) >> 16);
}
__device__ __forceinline__ u32 pk2(float a, float b) {
  return (u32)f2b(a) | ((u32)f2b(b) << 16);
}

typedef const __attribute__((address_space(1))) u32* gp_t;
typedef __attribute__((address_space(3))) u32* lp_t;
__device__ __forceinline__ void gld16(const u16* g, u16* l) {
  __builtin_amdgcn_global_load_lds((gp_t)g, (lp_t)l, 16, 0, 0);
}

#define CBAR() asm volatile("" ::: "memory")
#define BARRIER() do { CBAR(); __builtin_amdgcn_s_barrier(); CBAR(); } while (0)
#define VMC3() asm volatile("s_waitcnt vmcnt(3)" ::: "memory")
#define VMC0() asm volatile("s_waitcnt vmcnt(0)" ::: "memory")

// ---------------------------------------------------------------------------
// cvtS: f32 -> bf16 (RNE), 8 elems/thread. grid: 8192 x 256 for 16.8M elems.
// ---------------------------------------------------------------------------
__global__ __launch_bounds__(256) void cvtS(const float* __restrict__ S,
                                            u16* __restrict__ Sb) {
  const u64 idx = ((u64)blockIdx.x * 256 + threadIdx.x) * 8;
  const float4 a = *(const float4*)(S + idx);
  const float4 b = *(const float4*)(S + idx + 4);
  uint4 o;
  o.x = pk2(a.x, a.y); o.y = pk2(a.z, a.w);
  o.z = pk2(b.x, b.y); o.w = pk2(b.z, b.w);
  *(uint4*)(Sb + idx) = o;
}

// ---------------------------------------------------------------------------
// gemm256 (v4): 256x128 tile, BK=32, 8 waves (4Mx2N), per-wave 64x64 output
// (acc[4][4] = 64 regs -> <=128 VGPR/wave -> 4 waves/SIMD -> 2 blocks/CU).
// Triple-buffered LDS (3 x 24KB = 72KB <= 80KB for 2-block residency).
// Free-run, 1 barrier/K-tile, counted vmcnt(3) (tile T+2 stays in flight).
// Cross-block TLP covers barrier/vmcnt stalls that a single block cannot.
// XOR swizzle slot^=row&3 via pre-swizzled global source.
// C[m][c] = sum_k A[m][k]*B[c][k]; writes Ct[c][m]; optional 2*acc - Xt.
// grid (16, C/128), block 512.
// ---------------------------------------------------------------------------
__global__ __launch_bounds__(512, 4) void gemm256(const u16* __restrict__ A,
                                                  const u16* __restrict__ B,
                                                  u16* __restrict__ Ct,
                                                  const u16* __restrict__ Xt) {
  // buf k at k*12288 u16: A [256][32] at +0 (8192), B [128][32] at +8192 (4096)
  __shared__ __align__(16) u16 lds[36864];
  const int t = threadIdx.x;
  const int wave = t >> 6, lane = t & 63;
  const int q = lane >> 4, r16 = lane & 15;
  const int wmM = wave >> 1, wnN = wave & 1;

  // bijective XCD-chunk swizzle (nwg = 512 or 288, both % 8 == 0)
  const int nwg = (int)(gridDim.x * gridDim.y);
  const int bid = (int)(blockIdx.y * gridDim.x + blockIdx.x);
  const int swz = (bid & 7) * (nwg >> 3) + (bid >> 3);
  const int m0 = (swz & 15) << 8;   // gridDim.x == 16 always
  const int c0 = (swz >> 4) << 7;

  v4f acc[4][4];
  const v4f vz = {0.f, 0.f, 0.f, 0.f};
#pragma unroll
  for (int i = 0; i < 4; ++i)
#pragma unroll
    for (int j = 0; j < 4; ++j) acc[i][j] = vz;

  // staging: thread t covers row (t>>2) (0..127), 16B slot (t&3);
  // source col pre-swizzled by row&3 so swizzled ds_reads see linear data
  const int srow = t >> 2;
  const int sswz = ((t & 3) ^ (srow & 3)) << 3;       // element col offset
  const u16* pA0 = A + (u64)(m0 + srow) * NN + sswz;  // A rows 0..127
  const u16* pA1 = pA0 + (u64)128 * NN;               // A rows 128..255
  const u16* pB  = B + (u64)(c0 + srow) * NN + sswz;  // B rows 0..127
  u16* lw = lds + (wave << 9);                        // wave-uniform LDS dest

  // ds_read bases (u16 idx): row*32 + swizzled 16B slot*8
  const int fsw = (q ^ (r16 & 3)) << 3;
  const int aOff = ((wmM << 6) + r16) * 32 + fsw;          // + i*512
  const int bOff = 8192 + ((wnN << 6) + r16) * 32 + fsw;   // + j*512

  const int NT = NN >> 5;  // 128 K-tiles

#define STAGE(bufo, koff)                        \
  do {                                           \
    gld16(pA0 + (koff), lw + (bufo));            \
    gld16(pA1 + (koff), lw + (bufo) + 4096);     \
    gld16(pB + (koff),  lw + (bufo) + 8192);     \
  } while (0)

  // prologue: stage tile0 -> buf0, tile1 -> buf1
  STAGE(0, 0);
  STAGE(12288, 32);
  VMC3();           // tile0 landed; tile1 (3 ops) may remain in flight
  BARRIER();

  int br = 0;        // read buffer offset (tile T)
  int bs = 24576;    // stage buffer offset (tile T+2)
  int kk = 64;       // staging k offset (elems) for tile T+2
  for (int T = 0; T < NT; ++T) {
    // stage tile T+2 into buf (T+2)%3 (last read two tiles ago -> WAR safe
    // across the per-tile barrier)
    STAGE(bs, kk);
    VMC3();          // forces tile T+1 landed; T+2's 3 ops stay in flight

    v8s af[4], bf[4];
#pragma unroll
    for (int i = 0; i < 4; ++i)
      af[i] = *(const v8s*)(lds + br + aOff + (i << 9));
#pragma unroll
    for (int j = 0; j < 4; ++j)
      bf[j] = *(const v8s*)(lds + br + bOff + (j << 9));

    __builtin_amdgcn_s_setprio(1);
#pragma unroll
    for (int i = 0; i < 4; ++i)
#pragma unroll
      for (int j = 0; j < 4; ++j)
        acc[i][j] = __builtin_amdgcn_mfma_f32_16x16x32_bf16(af[i], bf[j], acc[i][j], 0, 0, 0);
    __builtin_amdgcn_s_setprio(0);

    BARRIER();       // tile boundary: all waves' reads consumed before next
                     // tile's staging into the 2-tiles-old buffer can land
    br += 12288; if (br == 36864) br = 0;
    bs += 12288; if (bs == 36864) bs = 0;
    kk += 32; if (kk > 4064) kk = 4064;   // clamped tail (harmless reloads)
  }
#undef STAGE

  // ---------------- epilogue: 128c x 256m C-tile through LDS, two halves ----
  VMC0();            // drain tail staging garbage before repurposing LDS
  __syncthreads();
  for (int h = 0; h < 2; ++h) {
    if (h) __syncthreads();
    if (wnN == h) {
#pragma unroll
      for (int i = 0; i < 4; ++i)
#pragma unroll
        for (int j = 0; j < 4; ++j) {
          const int cl = (j << 4) + r16;                    // 0..63 within half
          const int slot = (wmM << 3) + (i << 1) + (q >> 1);
          const int phys = (cl << 8) + ((slot ^ (cl & 7)) << 3) + ((q & 1) << 2);
          uint2 pv;
          pv.x = pk2(acc[i][j][0], acc[i][j][1]);
          pv.y = pk2(acc[i][j][2], acc[i][j][3]);
          *(uint2*)(lds + phys) = pv;
        }
    }
    __syncthreads();
#pragma unroll
    for (int it = 0; it < 4; ++it) {
      const int f = (it << 9) + t;
      const int cl = f >> 5, s = f & 31;
      const int phys = (cl << 8) + ((s ^ (cl & 7)) << 3);
      union { uint4 v; u16 e[8]; } tv;
      tv.v = *(const uint4*)(lds + phys);
      const u64 gi = (u64)(c0 + (h << 6) + cl) * NN + m0 + (s << 3);
      if (Xt) {
        union { uint4 v; u16 e[8]; } xv, ov;
        xv.v = *(const uint4*)(Xt + gi);
#pragma unroll
        for (int ss = 0; ss < 8; ++ss) ov.e[ss] = f2b(2.f * b2f(tv.e[ss]) - b2f(xv.e[ss]));
        *(uint4*)(Ct + gi) = ov.v;
      } else {
        *(uint4*)(Ct + gi) = tv.v;
      }
    }
  }
}

// ---------------------------------------------------------------------------
// gemm_s (fallback if workspace too small for bf16 S): A f32, in-loop cvt.
// ---------------------------------------------------------------------------
__global__ __launch_bounds__(256) void gemm_s(const float* __restrict__ A,
                                              const u16* __restrict__ B,
                                              u16* __restrict__ Ct,
                                              const u16* __restrict__ Xt) {
  __shared__ __align__(16) u16 As[4096];
  __shared__ __align__(16) u16 Bs[4096];
  __shared__ __align__(16) u16 T[16384];
  const int t = threadIdx.x;
  const int wave = t >> 6, lane = t & 63;
  const int m0 = blockIdx.x << 7, c0 = blockIdx.y << 7;
  const int wm = (wave >> 1) << 6, wc = (wave & 1) << 6;
  const int q = lane >> 4, r16 = lane & 15;
  v4f acc[4][4];
  const v4f vz = {0.f, 0.f, 0.f, 0.f};
#pragma unroll
  for (int i = 0; i < 4; ++i)
#pragma unroll
    for (int j = 0; j < 4; ++j) acc[i][j] = vz;

  const int sr = t >> 2;
  const int sc = (t & 3) << 3;
  const u64 abase = (u64)(m0 + sr) * NN + sc;
  const u64 bbase = (u64)(c0 + sr) * NN + sc;
  const u64 rstep = (u64)64 * NN;
  u16* as0 = As + sr * 32 + sc;
  u16* as1 = As + (64 + sr) * 32 + sc;
  u16* bs0 = Bs + sr * 32 + sc;
  u16* bs1 = Bs + (64 + sr) * 32 + sc;

  for (int k0 = 0; k0 < NN; k0 += 32) {
    const float4 a0l = *(const float4*)(A + abase + k0);
    const float4 a0h = *(const float4*)(A + abase + k0 + 4);
    const float4 a1l = *(const float4*)(A + abase + rstep + k0);
    const float4 a1h = *(const float4*)(A + abase + rstep + k0 + 4);
    const uint4 b0 = *(const uint4*)(B + bbase + k0);
    const uint4 b1 = *(const uint4*)(B + bbase + rstep + k0);
    uint4 pa0, pa1;
    pa0.x = pk2(a0l.x, a0l.y); pa0.y = pk2(a0l.z, a0l.w);
    pa0.z = pk2(a0h.x, a0h.y); pa0.w = pk2(a0h.z, a0h.w);
    pa1.x = pk2(a1l.x, a1l.y); pa1.y = pk2(a1l.z, a1l.w);
    pa1.z = pk2(a1h.x, a1h.y); pa1.w = pk2(a1h.z, a1h.w);
    __syncthreads();
    *(uint4*)as0 = pa0;
    *(uint4*)as1 = pa1;
    *(uint4*)bs0 = b0;
    *(uint4*)bs1 = b1;
    __syncthreads();
    v8s af[4], bf[4];
#pragma unroll
    for (int i = 0; i < 4; ++i)
      af[i] = *(const v8s*)(As + ((wm + i * 16 + r16) << 5) + (q << 3));
#pragma unroll
    for (int j = 0; j < 4; ++j)
      bf[j] = *(const v8s*)(Bs + ((wc + j * 16 + r16) << 5) + (q << 3));
#pragma unroll
    for (int i = 0; i < 4; ++i)
#pragma unroll
      for (int j = 0; j < 4; ++j)
        acc[i][j] = __builtin_amdgcn_mfma_f32_16x16x32_bf16(af[i], bf[j], acc[i][j], 0, 0, 0);
  }
#pragma unroll
  for (int i = 0; i < 4; ++i)
#pragma unroll
    for (int j = 0; j < 4; ++j) {
      const int cl = wc + j * 16 + r16;
      const int mm = wm + i * 16 + (q << 2);
      uint2 pv;
      pv.x = pk2(acc[i][j][0], acc[i][j][1]);
      pv.y = pk2(acc[i][j][2], acc[i][j][3]);
      *(uint2*)(T + (cl << 7) + mm) = pv;
    }
  __syncthreads();
#pragma unroll
  for (int it = 0; it < 8; ++it) {
    const int flat = it * 256 + t;
    const int cl = flat >> 4;
    const int seg = (flat & 15) << 3;
    const u64 gi = (u64)(c0 + cl) * NN + m0 + seg;
    union { uint4 v; u16 e[8]; } tv;
    tv.v = *(uint4*)(T + (cl << 7) + seg);
    if (Xt) {
      union { uint4 v; u16 e[8]; } xv, ov;
      xv.v = *(const uint4*)(Xt + gi);
#pragma unroll
      for (int s = 0; s < 8; ++s) ov.e[s] = f2b(2.f * b2f(tv.e[s]) - b2f(xv.e[s]));
      *(uint4*)(Ct + gi) = ov.v;
    } else {
      *(uint4*)(Ct + gi) = tv.v;
    }
  }
}

// ---------------------------------------------------------------------------
// Projection: out[b*JSTR + j][n] = act( sum_k Wt[j][k] * F[row(k,b)][n] + b[j] )
// ---------------------------------------------------------------------------
template <int DP, int KTOT>
__global__ __launch_bounds__(256) void proj_k(const u16* __restrict__ Wt,
                                              const u16* __restrict__ F,
                                              const float* __restrict__ bias,
                                              u16* __restrict__ outp,
                                              const int JSTR, const int ACT) {
  __shared__ __align__(16) u16 As2[2048];  // 64 j x 32 k
  __shared__ __align__(16) u16 Bs2[4096];  // 32 k x 128 n
  const int t = threadIdx.x;
  const int wave = t >> 6, lane = t & 63;
  const int q = lane >> 4, r16 = lane & 15;
  const int n0 = blockIdx.x << 7;
  const int j0 = blockIdx.y << 6;
  const int b = blockIdx.z;
  v4f acc[4][2];
  const v4f vz = {0.f, 0.f, 0.f, 0.f};
#pragma unroll
  for (int i = 0; i < 4; ++i) { acc[i][0] = vz; acc[i][1] = vz; }

  const int ar = t >> 2, ac = (t & 3) << 3;
  const u64 wbase = (u64)(j0 + ar) * KTOT + ac;

  for (int k0 = 0; k0 < KTOT; k0 += 32) {
    const uint4 av = *(const uint4*)(Wt + wbase + k0);
    uint4 bv[2];
#pragma unroll
    for (int ci = 0; ci < 2; ++ci) {
      const int c = ci * 256 + t;
      const int kr = c >> 4;
      const int seg = (c & 15) << 3;
      const int kk = k0 + kr;
      const int i = kk / DP;
      const int d = kk - i * DP;
      bv[ci] = *(const uint4*)(F + ((u64)i * (BATCH * DP) + (u64)b * DP + d) * NN + n0 + seg);
    }
    __syncthreads();
    *(uint4*)(As2 + ar * 32 + ac) = av;
#pragma unroll
    for (int ci = 0; ci < 2; ++ci) {
      const int c = ci * 256 + t;
      const int kr = c >> 4;
      const int seg = (c & 15) << 3;
      *(uint4*)(Bs2 + (kr << 7) + seg) = bv[ci];
    }
    __syncthreads();
    v8s af[4], bf[2];
#pragma unroll
    for (int i = 0; i < 4; ++i)
      af[i] = *(const v8s*)(As2 + ((i * 16 + r16) << 5) + (q << 3));
#pragma unroll
    for (int jj = 0; jj < 2; ++jj) {
      const int nn = (wave << 5) + jj * 16 + r16;
      v8s v;
#pragma unroll
      for (int s = 0; s < 8; ++s) v[s] = (short)Bs2[(((q << 3) + s) << 7) + nn];
      bf[jj] = v;
    }
#pragma unroll
    for (int i = 0; i < 4; ++i)
#pragma unroll
      for (int jj = 0; jj < 2; ++jj)
        acc[i][jj] = __builtin_amdgcn_mfma_f32_16x16x32_bf16(af[i], bf[jj], acc[i][jj], 0, 0, 0);
  }
#pragma unroll
  for (int i = 0; i < 4; ++i)
#pragma unroll
    for (int jj = 0; jj < 2; ++jj)
#pragma unroll
      for (int r = 0; r < 4; ++r) {
        const int j = j0 + i * 16 + (q << 2) + r;
        const int n = n0 + (wave << 5) + jj * 16 + r16;
        float v = acc[i][jj][r] + bias[j];
        v = ACT ? (1.f - 2.f / (__expf(2.f * v) + 1.f)) : (1.f / (1.f + __expf(-v)));
        outp[((u64)b * JSTR + j) * NN + n] = f2b(v);
      }
}

// ---------------------------------------------------------------------------
__global__ __launch_bounds__(256) void repackW(const float* __restrict__ W, u16* __restrict__ Wt,
                                               const int D, const int DP, const int KTOT,
                                               const int J) {
  const int idx = blockIdx.x * 256 + threadIdx.x;
  if (idx >= J * KTOT) return;
  const int j = idx / KTOT, k = idx - j * KTOT;
  const int i = k / DP, d = k - i * DP;
  u16 v = 0;
  if (i < 5 && d < D) v = f2b(W[(i * D + d) * J + j]);
  Wt[idx] = v;
}

// ---------------------------------------------------------------------------
__global__ __launch_bounds__(256) void pack0(const float* __restrict__ x,
                                             const float* __restrict__ hid0,
                                             u16* __restrict__ F0) {
  __shared__ __align__(16) u16 Hs[64 * 72];
  const int b = blockIdx.y, n0 = blockIdx.x << 6, t = threadIdx.x;
  const int r = t >> 2, ds = t & 3;
  const float* hrow = hid0 + ((u64)b * NN + n0 + r) * 64;
#pragma unroll
  for (int c4 = 0; c4 < 4; ++c4) {
    const float4 v = *(const float4*)(hrow + ds * 16 + c4 * 4);
    uint2 p;
    p.x = pk2(v.x, v.y);
    p.y = pk2(v.z, v.w);
    *(uint2*)(Hs + r * 72 + ds * 16 + c4 * 4) = p;
  }
  __syncthreads();
#pragma unroll
  for (int c2 = 0; c2 < 2; ++c2) {
    union { uint4 v; u16 h[8]; } o;
#pragma unroll
    for (int s = 0; s < 8; ++s) o.h[s] = Hs[(ds * 16 + c2 * 8 + s) * 72 + r];
    *(uint4*)(F0 + ((u64)b * 72 + 1 + r) * NN + n0 + ds * 16 + c2 * 8) = o.v;
  }
  if (t < 64) {
    F0[(u64)b * 72 * NN + n0 + t] = f2b(x[(u64)b * NN + n0 + t]);
  } else if (t < 120) {
    const int tt = t - 64;
    const int row = 65 + (tt >> 3), seg = (tt & 7) << 3;
    uint4 z; z.x = z.y = z.z = z.w = 0;
    *(uint4*)(F0 + ((u64)b * 72 + row) * NN + n0 + seg) = z;
  }
}

// ---------------------------------------------------------------------------
__global__ __launch_bounds__(256) void pack1(const float* __restrict__ hid1,
                                             u16* __restrict__ F1) {
  __shared__ __align__(16) u16 Hs[64 * 72];
  const int b = blockIdx.y, n0 = blockIdx.x << 6, t = threadIdx.x;
  const int r = t >> 2, ds = t & 3;
  const float* hrow = hid1 + ((u64)b * NN + n0 + r) * 64;
#pragma unroll
  for (int c4 = 0; c4 < 4; ++c4) {
    const float4 v = *(const float4*)(hrow + ds * 16 + c4 * 4);
    uint2 p;
    p.x = pk2(v.x, v.y);
    p.y = pk2(v.z, v.w);
    *(uint2*)(Hs + r * 72 + ds * 16 + c4 * 4) = p;
  }
  __syncthreads();
#pragma unroll
  for (int c2 = 0; c2 < 2; ++c2) {
    union { uint4 v; u16 h[8]; } o;
#pragma unroll
    for (int s = 0; s < 8; ++s) o.h[s] = Hs[(ds * 16 + c2 * 8 + s) * 72 + r];
    *(uint4*)(F1 + ((u64)b * 128 + 64 + r) * NN + n0 + ds * 16 + c2 * 8) = o.v;
  }
}

// ---------------------------------------------------------------------------
__global__ __launch_bounds__(256) void candpack(const u16* __restrict__ G, u16* __restrict__ F,
                                                const int DP, const int OFF) {
  const int u = blockIdx.x * 256 + threadIdx.x;
  const int b = u >> 15;
  const int d = (u >> 9) & 63;
  const int seg = (u & 511) << 3;
  union { uint4 v; u16 h[8]; } g, f, o;
  g.v = *(const uint4*)(G + ((u64)b * 128 + d) * NN + seg);
  u16* fp = F + ((u64)b * DP + OFF + d) * NN + seg;
  f.v = *(const uint4*)fp;
#pragma unroll
  for (int s = 0; s < 8; ++s) o.h[s] = f2b(b2f(f.h[s]) * b2f(g.h[s]));
  *(uint4*)fp = o.v;
}

// ---------------------------------------------------------------------------
__global__ __launch_bounds__(256) void hnew_k(const u16* __restrict__ G,
                                              const float* __restrict__ hidL,
                                              u16* __restrict__ HnF,
                                              float* __restrict__ outH) {
  __shared__ __align__(16) float Hs[64 * 72];
  __shared__ __align__(16) float T2[64 * 72];
  const int b = blockIdx.y, n0 = blockIdx.x << 6, t = threadIdx.x;
  const int r = t >> 2, ds = t & 3;
  const float* hrow = hidL + ((u64)b * NN + n0 + r) * 64;
#pragma unroll
  for (int c4 = 0; c4 < 4; ++c4)
    *(float4*)(Hs + r * 72 + ds * 16 + c4 * 4) = *(const float4*)(hrow + ds * 16 + c4 * 4);
  __syncthreads();
#pragma unroll
  for (int c2 = 0; c2 < 2; ++c2) {
    const int ncol = ds * 16 + c2 * 8;
    union { uint4 v; u16 h[8]; } uv, cv, o;
    uv.v = *(const uint4*)(G + ((u64)b * 128 + 64 + r) * NN + n0 + ncol);
    cv.v = *(const uint4*)(G + ((u64)b * 128 + r) * NN + n0 + ncol);
#pragma unroll
    for (int s = 0; s < 8; ++s) {
      const int nl = ncol + s;
      const float uu = b2f(uv.h[s]);
      const float hh = Hs[nl * 72 + r];
      const float cc = b2f(cv.h[s]);
      const float v = uu * hh + (1.f - uu) * cc;
      o.h[s] = f2b(v);
      T2[nl * 72 + r] = v;
    }
    *(uint4*)(HnF + ((u64)b * 128 + r) * NN + n0 + ncol) = o.v;
  }
  __syncthreads();
  const int nl2 = t >> 2, dseg = (t & 3) << 4;
#pragma unroll
  for (int c4 = 0; c4 < 4; ++c4) {
    const float4 v = *(const float4*)(T2 + nl2 * 72 + dseg + c4 * 4);
    *(float4*)(outH + ((u64)b * NN + n0 + nl2) * 64 + dseg + c4 * 4) = v;
  }
}

// ---------------------------------------------------------------------------
__global__ __launch_bounds__(256) void predictk(const float* __restrict__ H1bnd,
                                                const float* __restrict__ Wp,
                                                const float* __restrict__ bp,
                                                float* __restrict__ outp) {
  __shared__ float w[64];
  __shared__ float bb;
  const int t = threadIdx.x;
  if (t < 64) w[t] = Wp[t];
  if (t == 64) bb = bp[0];
  __syncthreads();
  const int idx = blockIdx.x * 256 + t;
  const float* h = H1bnd + (u64)idx * 64;
  float acc = bb;
#pragma unroll
  for (int c4 = 0; c4 < 16; ++c4) {
    const float4 v = *(const float4*)(h + c4 * 4);
    acc += v.x * w[c4 * 4] + v.y * w[c4 * 4 + 1] + v.z * w[c4 * 4 + 2] + v.w * w[c4 * 4 + 3];
  }
  outp[idx] = acc;
}

static inline void launch_gemm(bool big, const float* Af, const u16* Ab,
                               const u16* B, u16* Ct, const u16* Xt,
                               int Cdim, hipStream_t s) {
  if (big) gemm256<<<dim3(16, Cdim >> 7), 512, 0, s>>>(Ab, B, Ct, Xt);
  else     gemm_s<<<dim3(32, Cdim >> 7), 256, 0, s>>>(Af, B, Ct, Xt);
}

extern "C" void kernel_launch(void* const* d_in, const int* in_sizes, int n_in,
                              void* d_out, int out_size, void* d_ws, size_t ws_size,
                              hipStream_t stream) {
  const float* X   = (const float*)d_in[0];
  const float* HID = (const float*)d_in[1];
  const float* Sf  = (const float*)d_in[2];
  const float* Sb  = (const float*)d_in[3];
  const float* Wg0 = (const float*)d_in[4];
  const float* bg0 = (const float*)d_in[5];
  const float* Wc0 = (const float*)d_in[6];
  const float* bc0 = (const float*)d_in[7];
  const float* Wg1 = (const float*)d_in[8];
  const float* bg1 = (const float*)d_in[9];
  const float* Wc1 = (const float*)d_in[10];
  const float* bc1 = (const float*)d_in[11];
  const float* Wp  = (const float*)d_in[12];
  const float* bp  = (const float*)d_in[13];
  float* OUT = (float*)d_out;
  char* ws = (char*)d_ws;

  // workspace map (bytes):
  //   F  : 20480 rows x 4096 bf16 = 167,772,160
  //   G  : 32 x 128 x 4096 bf16   =  33,554,432
  //  [Sfb, Sbb : 4096x4096 bf16 each = 33,554,432 ea]  (if ws_size allows)
  //   WT : repacked weights       =     393,216
  u16* F = (u16*)(ws);
  u16* G = (u16*)(ws + 167772160ull);
  const u64 NEED_BIG = 167772160ull + 33554432ull + 2ull * 33554432ull + 393216ull;
  const bool big = ws_size >= NEED_BIG;
  u16* Sfb = (u16*)(ws + 167772160ull + 33554432ull);
  u16* Sbb = Sfb + (u64)NN * NN;
  u16* WT = big ? (Sbb + (u64)NN * NN)
                : (u16*)(ws + 167772160ull + 33554432ull);
  u16* Wg0t = WT;                   // 128 x 384
  u16* Wc0t = Wg0t + 128 * 384;     // 64 x 384
  u16* Wg1t = Wc0t + 64 * 384;      // 128 x 640
  u16* Wc1t = Wg1t + 128 * 640;     // 64 x 640

  const float* HID1 = HID + (u64)32 * 4096 * 64;
  float* OUT_H0 = OUT + 131072;
  float* OUT_H1 = OUT + 131072 + 8388608;

  // zero the layer-0 K-padding region of F (rows 11520..13823), read by proj i=5
  hipMemsetAsync(ws + (u64)11520 * NN * 2, 0, (u64)2304 * NN * 2, stream);

  if (big) {
    cvtS<<<8192, 256, 0, stream>>>(Sf, Sfb);
    cvtS<<<8192, 256, 0, stream>>>(Sb, Sbb);
  }

  repackW<<<(128 * 384 + 255) / 256, 256, 0, stream>>>(Wg0, Wg0t, 65, 72, 384, 128);
  repackW<<<(64 * 384 + 255) / 256, 256, 0, stream>>>(Wc0, Wc0t, 65, 72, 384, 64);
  repackW<<<(128 * 640 + 255) / 256, 256, 0, stream>>>(Wg1, Wg1t, 128, 128, 640, 128);
  repackW<<<(64 * 640 + 255) / 256, 256, 0, stream>>>(Wc1, Wc1t, 128, 128, 640, 64);

  // ---------------- layer 0 (Dp=72, C=2304) ----------------
  pack0<<<dim3(64, 32), 256, 0, stream>>>(X, HID, F);
  const u64 R0 = (u64)2304 * NN;
  launch_gemm(big, Sf, Sfb, F, F + R0, nullptr, 2304, stream);
  launch_gemm(big, Sb, Sbb, F, F + 3 * R0, nullptr, 2304, stream);
  launch_gemm(big, Sf, Sfb, F + R0, F + 2 * R0, F, 2304, stream);
  launch_gemm(big, Sb, Sbb, F + 3 * R0, F + 4 * R0, F, 2304, stream);
  proj_k<72, 384><<<dim3(32, 2, 32), 256, 0, stream>>>(Wg0t, F, bg0, G, 128, 0);
  candpack<<<4096, 256, 0, stream>>>(G, F, 72, 1);
  launch_gemm(big, Sf, Sfb, F, F + R0, nullptr, 2304, stream);
  launch_gemm(big, Sb, Sbb, F, F + 3 * R0, nullptr, 2304, stream);
  launch_gemm(big, Sf, Sfb, F + R0, F + 2 * R0, F, 2304, stream);
  launch_gemm(big, Sb, Sbb, F + 3 * R0, F + 4 * R0, F, 2304, stream);
  proj_k<72, 384><<<dim3(32, 1, 32), 256, 0, stream>>>(Wc0t, F, bc0, G, 128, 1);
  hnew_k<<<dim3(64, 32), 256, 0, stream>>>(G, HID, F, OUT_H0);

  // ---------------- layer 1 (Dp=128, C=4096) ----------------
  pack1<<<dim3(64, 32), 256, 0, stream>>>(HID1, F);
  const u64 R1 = (u64)4096 * NN;
  launch_gemm(big, Sf, Sfb, F, F + R1, nullptr, 4096, stream);
  launch_gemm(big, Sb, Sbb, F, F + 3 * R1, nullptr, 4096, stream);
  launch_gemm(big, Sf, Sfb, F + R1, F + 2 * R1, F, 4096, stream);
  launch_gemm(big, Sb, Sbb, F + 3 * R1, F + 4 * R1, F, 4096, stream);
  proj_k<128, 640><<<dim3(32, 2, 32), 256, 0, stream>>>(Wg1t, F, bg1, G, 128, 0);
  candpack<<<4096, 256, 0, stream>>>(G, F, 128, 64);
  launch_gemm(big, Sf, Sfb, F, F + R1, nullptr, 4096, stream);
  launch_gemm(big, Sb, Sbb, F, F + 3 * R1, nullptr, 4096, stream);
  launch_gemm(big, Sf, Sfb, F + R1, F + 2 * R1, F, 4096, stream);
  launch_gemm(big, Sb, Sbb, F + 3 * R1, F + 4 * R1, F, 4096, stream);
  proj_k<128, 640><<<dim3(32, 1, 32), 256, 0, stream>>>(Wc1t, F, bc1, G, 128, 1);
  hnew_k<<<dim3(64, 32), 256, 0, stream>>>(G, HID1, F, OUT_H1);

  predictk<<<512, 256, 0, stream>>>(OUT_H1, Wp, bp, OUT);
}

// Round 5
// 2056.355 us; speedup vs baseline: 1.1946x; 1.1946x over previous
//
#include <hip/hip_runtime.h>

typedef unsigned short u16;
typedef unsigned int u32;
typedef unsigned long long u64;
typedef short v8s __attribute__((ext_vector_type(8)));
typedef float v4f __attribute__((ext_vector_type(4)));

#define NN 4096
#define BATCH 32

__device__ __forceinline__ float b2f(u16 u) {
  union { u32 i; float f; } c; c.i = ((u32)u) << 16; return c.f;
}
__device__ __forceinline__ u16 f2b(float f) {
  union { float f; u32 i; } c; c.f = f;
  u32 x = c.i;
  return (u16)((x + 0x7fffu + ((x >> 16) & 1u)) >> 16);
}
__device__ __forceinline__ u32 pk2(float a, float b) {
  return (u32)f2b(a) | ((u32)f2b(b) << 16);
}

typedef const __attribute__((address_space(1))) u32* gp_t;
typedef __attribute__((address_space(3))) u32* lp_t;
__device__ __forceinline__ void gld16(const u16* g, u16* l) {
  __builtin_amdgcn_global_load_lds((gp_t)g, (lp_t)l, 16, 0, 0);
}

#define CBAR() asm volatile("" ::: "memory")
#define BARRIER() do { CBAR(); __builtin_amdgcn_s_barrier(); CBAR(); } while (0)
#define LGKM0() asm volatile("s_waitcnt lgkmcnt(0)" ::: "memory")
#define VMC4() asm volatile("s_waitcnt vmcnt(4)" ::: "memory")
#define VMC0() asm volatile("s_waitcnt vmcnt(0)" ::: "memory")

// ---------------------------------------------------------------------------
// cvtS: f32 -> bf16 (RNE), 8 elems/thread. grid: 8192 x 256 for 16.8M elems.
// ---------------------------------------------------------------------------
__global__ __launch_bounds__(256) void cvtS(const float* __restrict__ S,
                                            u16* __restrict__ Sb) {
  const u64 idx = ((u64)blockIdx.x * 256 + threadIdx.x) * 8;
  const float4 a = *(const float4*)(S + idx);
  const float4 b = *(const float4*)(S + idx + 4);
  uint4 o;
  o.x = pk2(a.x, a.y); o.y = pk2(a.z, a.w);
  o.z = pk2(b.x, b.y); o.w = pk2(b.z, b.w);
  *(uint4*)(Sb + idx) = o;
}

// ---------------------------------------------------------------------------
// gemm256 (R3, verified 103.7us): 256x256 tile, BK=64, 8 waves (2Mx4N).
// Minimal-barrier free-run schedule + one-cluster-ahead operand pipelining.
// grid (16, C/256), block 512.
// ---------------------------------------------------------------------------
__global__ __launch_bounds__(512, 2) void gemm256(const u16* __restrict__ A,
                                                  const u16* __restrict__ B,
                                                  u16* __restrict__ Ct,
                                                  const u16* __restrict__ Xt) {
  // 128 KiB: buf b at b*32768 (u16); regions A-h0 0 | A-h1 8192 | B-h0 16384 | B-h1 24576
  __shared__ __align__(16) u16 lds[65536];
  const int t = threadIdx.x;
  const int wave = t >> 6, lane = t & 63;
  const int q = lane >> 4, r16 = lane & 15;
  const int wm = wave >> 2, wn = wave & 3;

  const int nwg = (int)(gridDim.x * gridDim.y);
  const int bid = (int)(blockIdx.y * gridDim.x + blockIdx.x);
  const int swz = (bid & 7) * (nwg >> 3) + (bid >> 3);
  const int m0 = (swz & 15) << 8;   // gridDim.x == 16 always
  const int c0 = (swz >> 4) << 8;

  v4f acc[8][4];
  const v4f vz = {0.f, 0.f, 0.f, 0.f};
#pragma unroll
  for (int i = 0; i < 8; ++i)
#pragma unroll
    for (int j = 0; j < 4; ++j) acc[i][j] = vz;

  const int srow = t >> 3;
  const int sslot = ((t & 7) ^ (srow & 7)) << 3;      // element col offset
  const u16* pA = A + (u64)(m0 + srow) * NN + sslot;
  const u16* pB = B + (u64)(c0 + srow) * NN + sslot;
  const u64 rstep = (u64)64 * NN;
  const u64 hstep = (u64)128 * NN;
  u16* lw = lds + (wave << 9);

  const int sw8 = (q ^ (r16 & 7)) << 3;
  const int aBase = (wm << 13) + (r16 << 6) + sw8;
  const int bBase = 16384 + ((wn >> 1) << 13) + ((wn & 1) << 12) + (r16 << 6) + sw8;

  const int NT = NN >> 6;  // 64 K-tiles

  gld16(pA, lw);
  gld16(pA + rstep, lw + 4096);
  gld16(pA + hstep, lw + 8192);
  gld16(pA + hstep + rstep, lw + 12288);
  gld16(pB, lw + 16384);
  gld16(pB + rstep, lw + 20480);
  gld16(pB + hstep, lw + 24576);
  gld16(pB + hstep + rstep, lw + 28672);
  gld16(pB + 64, lw + 32768 + 16384);
  gld16(pB + 64 + rstep, lw + 32768 + 20480);
  gld16(pB + 64 + hstep, lw + 32768 + 24576);
  gld16(pB + 64 + hstep + rstep, lw + 32768 + 28672);
  VMC4();
  BARRIER();

  v8s af[4][2], bf01[2][2], bf23[2][2];
#pragma unroll
  for (int i = 0; i < 4; ++i) {
    const int a = aBase + (i << 10);
    af[i][0] = *(const v8s*)(lds + a);
    af[i][1] = *(const v8s*)(lds + (a ^ 32));
  }
#pragma unroll
  for (int j = 0; j < 2; ++j) {
    const int b = bBase + (j << 10);
    bf01[j][0] = *(const v8s*)(lds + b);
    bf01[j][1] = *(const v8s*)(lds + (b ^ 32));
  }

#pragma unroll 2
  for (int T = 0; T < NT; ++T) {
    const int bo = (T & 1) << 15;
    const int no = bo ^ 32768;
    const u64 ka = (u64)(T + 1 < NT ? T + 1 : NT - 1) << 6;
    const u64 kb = (u64)(T + 2 < NT ? T + 2 : NT - 1) << 6;

    // ---- phase 0
    gld16(pA + ka, lw + no);
    gld16(pA + ka + rstep, lw + no + 4096);
#pragma unroll
    for (int j = 0; j < 2; ++j) {
      const int b = bo + bBase + ((2 + j) << 10);
      bf23[j][0] = *(const v8s*)(lds + b);
      bf23[j][1] = *(const v8s*)(lds + (b ^ 32));
    }
    __builtin_amdgcn_s_setprio(1);
#pragma unroll
    for (int i = 0; i < 4; ++i)
#pragma unroll
      for (int j = 0; j < 2; ++j) {
        acc[i][j] = __builtin_amdgcn_mfma_f32_16x16x32_bf16(af[i][0], bf01[j][0], acc[i][j], 0, 0, 0);
        acc[i][j] = __builtin_amdgcn_mfma_f32_16x16x32_bf16(af[i][1], bf01[j][1], acc[i][j], 0, 0, 0);
      }
    __builtin_amdgcn_s_setprio(0);

    // ---- phase 1
    gld16(pA + hstep + ka, lw + no + 8192);
    gld16(pA + hstep + ka + rstep, lw + no + 12288);
    LGKM0();
    BARRIER();
    __builtin_amdgcn_s_setprio(1);
#pragma unroll
    for (int i = 0; i < 4; ++i)
#pragma unroll
      for (int j = 0; j < 2; ++j) {
        acc[i][2 + j] = __builtin_amdgcn_mfma_f32_16x16x32_bf16(af[i][0], bf23[j][0], acc[i][2 + j], 0, 0, 0);
        acc[i][2 + j] = __builtin_amdgcn_mfma_f32_16x16x32_bf16(af[i][1], bf23[j][1], acc[i][2 + j], 0, 0, 0);
      }
    __builtin_amdgcn_s_setprio(0);
#pragma unroll
    for (int i = 0; i < 4; ++i) {
      const int a = bo + aBase + ((4 + i) << 10);
      af[i][0] = *(const v8s*)(lds + a);
      af[i][1] = *(const v8s*)(lds + (a ^ 32));
    }
    __builtin_amdgcn_sched_barrier(0);

    // ---- phase 2
    gld16(pB + kb, lw + bo + 16384);
    gld16(pB + kb + rstep, lw + bo + 20480);
    __builtin_amdgcn_s_setprio(1);
#pragma unroll
    for (int i = 0; i < 4; ++i)
#pragma unroll
      for (int j = 0; j < 2; ++j) {
        acc[4 + i][2 + j] = __builtin_amdgcn_mfma_f32_16x16x32_bf16(af[i][0], bf23[j][0], acc[4 + i][2 + j], 0, 0, 0);
        acc[4 + i][2 + j] = __builtin_amdgcn_mfma_f32_16x16x32_bf16(af[i][1], bf23[j][1], acc[4 + i][2 + j], 0, 0, 0);
      }
    __builtin_amdgcn_s_setprio(0);

    // ---- phase 3
    gld16(pB + hstep + kb, lw + bo + 24576);
    gld16(pB + hstep + kb + rstep, lw + bo + 28672);
    VMC4();
    BARRIER();
    __builtin_amdgcn_s_setprio(1);
#pragma unroll
    for (int i = 0; i < 4; ++i)
#pragma unroll
      for (int j = 0; j < 2; ++j) {
        acc[4 + i][j] = __builtin_amdgcn_mfma_f32_16x16x32_bf16(af[i][0], bf01[j][0], acc[4 + i][j], 0, 0, 0);
        acc[4 + i][j] = __builtin_amdgcn_mfma_f32_16x16x32_bf16(af[i][1], bf01[j][1], acc[4 + i][j], 0, 0, 0);
      }
    __builtin_amdgcn_s_setprio(0);
#pragma unroll
    for (int i = 0; i < 4; ++i) {
      const int a = no + aBase + (i << 10);
      af[i][0] = *(const v8s*)(lds + a);
      af[i][1] = *(const v8s*)(lds + (a ^ 32));
    }
#pragma unroll
    for (int j = 0; j < 2; ++j) {
      const int b = no + bBase + (j << 10);
      bf01[j][0] = *(const v8s*)(lds + b);
      bf01[j][1] = *(const v8s*)(lds + (b ^ 32));
    }
    __builtin_amdgcn_sched_barrier(0);
  }

  // ---------------- epilogue ----------------
  VMC0();
  __syncthreads();
#pragma unroll
  for (int i = 0; i < 8; ++i)
#pragma unroll
    for (int j = 0; j < 4; ++j) {
      const int cl = (wn << 6) + (j << 4) + r16;
      const int ml = (wm << 7) + (i << 4) + (q << 2);
      const int phys = (cl << 8) + ((((ml >> 3) ^ (cl & 7)) << 3) | (ml & 7));
      uint2 pv;
      pv.x = pk2(acc[i][j][0], acc[i][j][1]);
      pv.y = pk2(acc[i][j][2], acc[i][j][3]);
      *(uint2*)(lds + phys) = pv;
    }
  __syncthreads();
#pragma unroll
  for (int it = 0; it < 16; ++it) {
    const int f = (it << 9) + t;
    const int cl = f >> 5, sl = f & 31;
    const int phys = (cl << 8) + ((sl ^ (cl & 7)) << 3);
    union { uint4 v; u16 e[8]; } tv;
    tv.v = *(const uint4*)(lds + phys);
    const u64 gi = (u64)(c0 + cl) * NN + m0 + (sl << 3);
    if (Xt) {
      union { uint4 v; u16 e[8]; } xv, ov;
      xv.v = *(const uint4*)(Xt + gi);
#pragma unroll
      for (int s = 0; s < 8; ++s) ov.e[s] = f2b(2.f * b2f(tv.e[s]) - b2f(xv.e[s]));
      *(uint4*)(Ct + gi) = ov.v;
    } else {
      *(uint4*)(Ct + gi) = tv.v;
    }
  }
}

// ---------------------------------------------------------------------------
// gemm_h: paired half-M GEMM for layer-0 tail packing. 128x256 tile, BK=64,
// 8 waves (2Mx4N), per-wave 64x64 (acc[4][4]). blockIdx.z selects
// (A,B,C) for the two independent GEMMs {Sf*X0, Sb*X1}. Same 2-barrier
// free-run schedule + drain-before-barrier invariants as gemm256.
// grid (32, 9, 2), block 512. LDS 96 KB (2 bufs x {A[128][64] | B[256][64]}).
// ---------------------------------------------------------------------------
__global__ __launch_bounds__(512, 2) void gemm_h(const u16* __restrict__ A0f,
                                                 const u16* __restrict__ A1f,
                                                 const u16* __restrict__ B0f,
                                                 const u16* __restrict__ B1f,
                                                 u16* __restrict__ C0f,
                                                 u16* __restrict__ C1f,
                                                 const u16* __restrict__ Xt) {
  __shared__ __align__(16) u16 lds[49152];  // 2 x 24576: A 0..8191 | B 8192..24575
  const int t = threadIdx.x;
  const int wave = t >> 6, lane = t & 63;
  const int q = lane >> 4, r16 = lane & 15;
  const int wm = wave >> 2, wn = wave & 3;   // wm 0..1 (M), wn 0..3 (C)
  const int z = blockIdx.z;
  const u16* A = z ? A1f : A0f;
  const u16* B = z ? B1f : B0f;
  u16* C = z ? C1f : C0f;

  // per-z-plane bijective XCD swizzle (nwg = 288, % 8 == 0)
  const int nwg = (int)(gridDim.x * gridDim.y);
  const int bid = (int)(blockIdx.y * gridDim.x + blockIdx.x);
  const int swz = (bid & 7) * (nwg >> 3) + (bid >> 3);
  const int m0 = (swz & 31) << 7;   // gridDim.x == 32
  const int c0 = (swz >> 5) << 8;

  v4f acc[4][4];
  const v4f vz = {0.f, 0.f, 0.f, 0.f};
#pragma unroll
  for (int i = 0; i < 4; ++i)
#pragma unroll
    for (int j = 0; j < 4; ++j) acc[i][j] = vz;

  const int srow = t >> 3;
  const int sslot = ((t & 7) ^ (srow & 7)) << 3;
  const u16* pA = A + (u64)(m0 + srow) * NN + sslot;
  const u16* pB = B + (u64)(c0 + srow) * NN + sslot;
  const u64 rstep = (u64)64 * NN;
  u16* lw = lds + (wave << 9);

  const int sw8 = (q ^ (r16 & 7)) << 3;
  const int aBase = (wm << 12) + (r16 << 6) + sw8;          // + i<<10
  const int bBase = 8192 + (wn << 12) + (r16 << 6) + sw8;   // + j<<10

  const int NT = NN >> 6;  // 64 K-tiles

#define STAGE_A(bufo, koff)                        \
  do {                                             \
    gld16(pA + (koff), lw + (bufo));               \
    gld16(pA + rstep + (koff), lw + (bufo) + 4096);\
  } while (0)
#define STAGE_B(bufo, koff)                                    \
  do {                                                         \
    gld16(pB + (koff), lw + (bufo) + 8192);                    \
    gld16(pB + rstep + (koff), lw + (bufo) + 12288);           \
    gld16(pB + 2 * rstep + (koff), lw + (bufo) + 16384);       \
    gld16(pB + 3 * rstep + (koff), lw + (bufo) + 20480);       \
  } while (0)

  // prologue: A(0), B(0), B(1). VMC4 leaves B(1)'s 4 ops in flight.
  STAGE_A(0, 0);
  STAGE_B(0, 0);
  STAGE_B(24576, 64);
  VMC4();
  BARRIER();

  v8s af[4][2], bf01[2][2], bf23[2][2];
#pragma unroll
  for (int i = 0; i < 4; ++i) {
    const int a = aBase + (i << 10);
    af[i][0] = *(const v8s*)(lds + a);
    af[i][1] = *(const v8s*)(lds + (a ^ 32));
  }
#pragma unroll
  for (int j = 0; j < 2; ++j) {
    const int b = bBase + (j << 10);
    bf01[j][0] = *(const v8s*)(lds + b);
    bf01[j][1] = *(const v8s*)(lds + (b ^ 32));
  }

  for (int T = 0; T < NT; ++T) {
    const int bo = (T & 1) ? 24576 : 0;
    const int no = bo ^ 24576;
    const u64 ka = (u64)(T + 1 < NT ? T + 1 : NT - 1) << 6;
    const u64 kb = (u64)(T + 2 < NT ? T + 2 : NT - 1) << 6;

    // ---- phase A: stage A(T+1) | read bf23 | MFMA C0 (af x bf01)
    STAGE_A(no, ka);
#pragma unroll
    for (int j = 0; j < 2; ++j) {
      const int b = bo + bBase + ((2 + j) << 10);
      bf23[j][0] = *(const v8s*)(lds + b);
      bf23[j][1] = *(const v8s*)(lds + (b ^ 32));
    }
    __builtin_amdgcn_s_setprio(1);
#pragma unroll
    for (int i = 0; i < 4; ++i)
#pragma unroll
      for (int j = 0; j < 2; ++j) {
        acc[i][j] = __builtin_amdgcn_mfma_f32_16x16x32_bf16(af[i][0], bf01[j][0], acc[i][j], 0, 0, 0);
        acc[i][j] = __builtin_amdgcn_mfma_f32_16x16x32_bf16(af[i][1], bf01[j][1], acc[i][j], 0, 0, 0);
      }
    __builtin_amdgcn_s_setprio(0);
    LGKM0();     // bf23 in regs before crossing the WAR barrier
    BARRIER();   // all waves' B reads done before B(T+2) staging

    // ---- phase B: stage B(T+2) into bo.B | drain T+1 | MFMA C1 | prefetch
    STAGE_B(bo, kb);
    VMC4();      // drains B(T+1)+A(T+1); leaves B(T+2) 4 ops in flight
    BARRIER();   // T+1 fully visible to all waves
    __builtin_amdgcn_s_setprio(1);
#pragma unroll
    for (int i = 0; i < 4; ++i)
#pragma unroll
      for (int j = 0; j < 2; ++j) {
        acc[i][2 + j] = __builtin_amdgcn_mfma_f32_16x16x32_bf16(af[i][0], bf23[j][0], acc[i][2 + j], 0, 0, 0);
        acc[i][2 + j] = __builtin_amdgcn_mfma_f32_16x16x32_bf16(af[i][1], bf23[j][1], acc[i][2 + j], 0, 0, 0);
      }
    __builtin_amdgcn_s_setprio(0);
#pragma unroll
    for (int i = 0; i < 4; ++i) {
      const int a = no + aBase + (i << 10);
      af[i][0] = *(const v8s*)(lds + a);
      af[i][1] = *(const v8s*)(lds + (a ^ 32));
    }
#pragma unroll
    for (int j = 0; j < 2; ++j) {
      const int b = no + bBase + (j << 10);
      bf01[j][0] = *(const v8s*)(lds + b);
      bf01[j][1] = *(const v8s*)(lds + (b ^ 32));
    }
    __builtin_amdgcn_sched_barrier(0);
  }
#undef STAGE_A
#undef STAGE_B

  // ---------------- epilogue: 256c x 128m through LDS ----------------
  VMC0();
  __syncthreads();
#pragma unroll
  for (int i = 0; i < 4; ++i)
#pragma unroll
    for (int j = 0; j < 4; ++j) {
      const int cl = (wn << 6) + (j << 4) + r16;               // 0..255
      const int slot = (wm << 3) + (i << 1) + (q >> 1);        // 0..15
      const int phys = (cl << 7) + ((slot ^ (cl & 7)) << 3) + ((q & 1) << 2);
      uint2 pv;
      pv.x = pk2(acc[i][j][0], acc[i][j][1]);
      pv.y = pk2(acc[i][j][2], acc[i][j][3]);
      *(uint2*)(lds + phys) = pv;
    }
  __syncthreads();
#pragma unroll
  for (int it = 0; it < 8; ++it) {
    const int f = (it << 9) + t;
    const int cl = f >> 4, sl = f & 15;
    const int phys = (cl << 7) + ((sl ^ (cl & 7)) << 3);
    union { uint4 v; u16 e[8]; } tv;
    tv.v = *(const uint4*)(lds + phys);
    const u64 gi = (u64)(c0 + cl) * NN + m0 + (sl << 3);
    if (Xt) {
      union { uint4 v; u16 e[8]; } xv, ov;
      xv.v = *(const uint4*)(Xt + gi);
#pragma unroll
      for (int s = 0; s < 8; ++s) ov.e[s] = f2b(2.f * b2f(tv.e[s]) - b2f(xv.e[s]));
      *(uint4*)(C + gi) = ov.v;
    } else {
      *(uint4*)(C + gi) = tv.v;
    }
  }
}

// ---------------------------------------------------------------------------
// gemm_s (fallback if workspace too small for bf16 S): A f32, in-loop cvt.
// ---------------------------------------------------------------------------
__global__ __launch_bounds__(256) void gemm_s(const float* __restrict__ A,
                                              const u16* __restrict__ B,
                                              u16* __restrict__ Ct,
                                              const u16* __restrict__ Xt) {
  __shared__ __align__(16) u16 As[4096];
  __shared__ __align__(16) u16 Bs[4096];
  __shared__ __align__(16) u16 T[16384];
  const int t = threadIdx.x;
  const int wave = t >> 6, lane = t & 63;
  const int m0 = blockIdx.x << 7, c0 = blockIdx.y << 7;
  const int wm = (wave >> 1) << 6, wc = (wave & 1) << 6;
  const int q = lane >> 4, r16 = lane & 15;
  v4f acc[4][4];
  const v4f vz = {0.f, 0.f, 0.f, 0.f};
#pragma unroll
  for (int i = 0; i < 4; ++i)
#pragma unroll
    for (int j = 0; j < 4; ++j) acc[i][j] = vz;

  const int sr = t >> 2;
  const int sc = (t & 3) << 3;
  const u64 abase = (u64)(m0 + sr) * NN + sc;
  const u64 bbase = (u64)(c0 + sr) * NN + sc;
  const u64 rstep = (u64)64 * NN;
  u16* as0 = As + sr * 32 + sc;
  u16* as1 = As + (64 + sr) * 32 + sc;
  u16* bs0 = Bs + sr * 32 + sc;
  u16* bs1 = Bs + (64 + sr) * 32 + sc;

  for (int k0 = 0; k0 < NN; k0 += 32) {
    const float4 a0l = *(const float4*)(A + abase + k0);
    const float4 a0h = *(const float4*)(A + abase + k0 + 4);
    const float4 a1l = *(const float4*)(A + abase + rstep + k0);
    const float4 a1h = *(const float4*)(A + abase + rstep + k0 + 4);
    const uint4 b0 = *(const uint4*)(B + bbase + k0);
    const uint4 b1 = *(const uint4*)(B + bbase + rstep + k0);
    uint4 pa0, pa1;
    pa0.x = pk2(a0l.x, a0l.y); pa0.y = pk2(a0l.z, a0l.w);
    pa0.z = pk2(a0h.x, a0h.y); pa0.w = pk2(a0h.z, a0h.w);
    pa1.x = pk2(a1l.x, a1l.y); pa1.y = pk2(a1l.z, a1l.w);
    pa1.z = pk2(a1h.x, a1h.y); pa1.w = pk2(a1h.z, a1h.w);
    __syncthreads();
    *(uint4*)as0 = pa0;
    *(uint4*)as1 = pa1;
    *(uint4*)bs0 = b0;
    *(uint4*)bs1 = b1;
    __syncthreads();
    v8s af[4], bf[4];
#pragma unroll
    for (int i = 0; i < 4; ++i)
      af[i] = *(const v8s*)(As + ((wm + i * 16 + r16) << 5) + (q << 3));
#pragma unroll
    for (int j = 0; j < 4; ++j)
      bf[j] = *(const v8s*)(Bs + ((wc + j * 16 + r16) << 5) + (q << 3));
#pragma unroll
    for (int i = 0; i < 4; ++i)
#pragma unroll
      for (int j = 0; j < 4; ++j)
        acc[i][j] = __builtin_amdgcn_mfma_f32_16x16x32_bf16(af[i], bf[j], acc[i][j], 0, 0, 0);
  }
#pragma unroll
  for (int i = 0; i < 4; ++i)
#pragma unroll
    for (int j = 0; j < 4; ++j) {
      const int cl = wc + j * 16 + r16;
      const int mm = wm + i * 16 + (q << 2);
      uint2 pv;
      pv.x = pk2(acc[i][j][0], acc[i][j][1]);
      pv.y = pk2(acc[i][j][2], acc[i][j][3]);
      *(uint2*)(T + (cl << 7) + mm) = pv;
    }
  __syncthreads();
#pragma unroll
  for (int it = 0; it < 8; ++it) {
    const int flat = it * 256 + t;
    const int cl = flat >> 4;
    const int seg = (flat & 15) << 3;
    const u64 gi = (u64)(c0 + cl) * NN + m0 + seg;
    union { uint4 v; u16 e[8]; } tv;
    tv.v = *(uint4*)(T + (cl << 7) + seg);
    if (Xt) {
      union { uint4 v; u16 e[8]; } xv, ov;
      xv.v = *(const uint4*)(Xt + gi);
#pragma unroll
      for (int s = 0; s < 8; ++s) ov.e[s] = f2b(2.f * b2f(tv.e[s]) - b2f(xv.e[s]));
      *(uint4*)(Ct + gi) = ov.v;
    } else {
      *(uint4*)(Ct + gi) = tv.v;
    }
  }
}

// ---------------------------------------------------------------------------
// Projection: out[b*JSTR + j][n] = act( sum_k Wt[j][k] * F[row(k,b)][n] + b[j] )
// ---------------------------------------------------------------------------
template <int DP, int KTOT>
__global__ __launch_bounds__(256) void proj_k(const u16* __restrict__ Wt,
                                              const u16* __restrict__ F,
                                              const float* __restrict__ bias,
                                              u16* __restrict__ outp,
                                              const int JSTR, const int ACT) {
  __shared__ __align__(16) u16 As2[2048];  // 64 j x 32 k
  __shared__ __align__(16) u16 Bs2[4096];  // 32 k x 128 n
  const int t = threadIdx.x;
  const int wave = t >> 6, lane = t & 63;
  const int q = lane >> 4, r16 = lane & 15;
  const int n0 = blockIdx.x << 7;
  const int j0 = blockIdx.y << 6;
  const int b = blockIdx.z;
  v4f acc[4][2];
  const v4f vz = {0.f, 0.f, 0.f, 0.f};
#pragma unroll
  for (int i = 0; i < 4; ++i) { acc[i][0] = vz; acc[i][1] = vz; }

  const int ar = t >> 2, ac = (t & 3) << 3;
  const u64 wbase = (u64)(j0 + ar) * KTOT + ac;

  for (int k0 = 0; k0 < KTOT; k0 += 32) {
    const uint4 av = *(const uint4*)(Wt + wbase + k0);
    uint4 bv[2];
#pragma unroll
    for (int ci = 0; ci < 2; ++ci) {
      const int c = ci * 256 + t;
      const int kr = c >> 4;
      const int seg = (c & 15) << 3;
      const int kk = k0 + kr;
      const int i = kk / DP;
      const int d = kk - i * DP;
      bv[ci] = *(const uint4*)(F + ((u64)i * (BATCH * DP) + (u64)b * DP + d) * NN + n0 + seg);
    }
    __syncthreads();
    *(uint4*)(As2 + ar * 32 + ac) = av;
#pragma unroll
    for (int ci = 0; ci < 2; ++ci) {
      const int c = ci * 256 + t;
      const int kr = c >> 4;
      const int seg = (c & 15) << 3;
      *(uint4*)(Bs2 + (kr << 7) + seg) = bv[ci];
    }
    __syncthreads();
    v8s af[4], bf[2];
#pragma unroll
    for (int i = 0; i < 4; ++i)
      af[i] = *(const v8s*)(As2 + ((i * 16 + r16) << 5) + (q << 3));
#pragma unroll
    for (int jj = 0; jj < 2; ++jj) {
      const int nn = (wave << 5) + jj * 16 + r16;
      v8s v;
#pragma unroll
      for (int s = 0; s < 8; ++s) v[s] = (short)Bs2[(((q << 3) + s) << 7) + nn];
      bf[jj] = v;
    }
#pragma unroll
    for (int i = 0; i < 4; ++i)
#pragma unroll
      for (int jj = 0; jj < 2; ++jj)
        acc[i][jj] = __builtin_amdgcn_mfma_f32_16x16x32_bf16(af[i], bf[jj], acc[i][jj], 0, 0, 0);
  }
#pragma unroll
  for (int i = 0; i < 4; ++i)
#pragma unroll
    for (int jj = 0; jj < 2; ++jj)
#pragma unroll
      for (int r = 0; r < 4; ++r) {
        const int j = j0 + i * 16 + (q << 2) + r;
        const int n = n0 + (wave << 5) + jj * 16 + r16;
        float v = acc[i][jj][r] + bias[j];
        v = ACT ? (1.f - 2.f / (__expf(2.f * v) + 1.f)) : (1.f / (1.f + __expf(-v)));
        outp[((u64)b * JSTR + j) * NN + n] = f2b(v);
      }
}

// ---------------------------------------------------------------------------
__global__ __launch_bounds__(256) void repackW(const float* __restrict__ W, u16* __restrict__ Wt,
                                               const int D, const int DP, const int KTOT,
                                               const int J) {
  const int idx = blockIdx.x * 256 + threadIdx.x;
  if (idx >= J * KTOT) return;
  const int j = idx / KTOT, k = idx - j * KTOT;
  const int i = k / DP, d = k - i * DP;
  u16 v = 0;
  if (i < 5 && d < D) v = f2b(W[(i * D + d) * J + j]);
  Wt[idx] = v;
}

// ---------------------------------------------------------------------------
__global__ __launch_bounds__(256) void pack0(const float* __restrict__ x,
                                             const float* __restrict__ hid0,
                                             u16* __restrict__ F0) {
  __shared__ __align__(16) u16 Hs[64 * 72];
  const int b = blockIdx.y, n0 = blockIdx.x << 6, t = threadIdx.x;
  const int r = t >> 2, ds = t & 3;
  const float* hrow = hid0 + ((u64)b * NN + n0 + r) * 64;
#pragma unroll
  for (int c4 = 0; c4 < 4; ++c4) {
    const float4 v = *(const float4*)(hrow + ds * 16 + c4 * 4);
    uint2 p;
    p.x = pk2(v.x, v.y);
    p.y = pk2(v.z, v.w);
    *(uint2*)(Hs + r * 72 + ds * 16 + c4 * 4) = p;
  }
  __syncthreads();
#pragma unroll
  for (int c2 = 0; c2 < 2; ++c2) {
    union { uint4 v; u16 h[8]; } o;
#pragma unroll
    for (int s = 0; s < 8; ++s) o.h[s] = Hs[(ds * 16 + c2 * 8 + s) * 72 + r];
    *(uint4*)(F0 + ((u64)b * 72 + 1 + r) * NN + n0 + ds * 16 + c2 * 8) = o.v;
  }
  if (t < 64) {
    F0[(u64)b * 72 * NN + n0 + t] = f2b(x[(u64)b * NN + n0 + t]);
  } else if (t < 120) {
    const int tt = t - 64;
    const int row = 65 + (tt >> 3), seg = (tt & 7) << 3;
    uint4 z; z.x = z.y = z.z = z.w = 0;
    *(uint4*)(F0 + ((u64)b * 72 + row) * NN + n0 + seg) = z;
  }
}

// ---------------------------------------------------------------------------
__global__ __launch_bounds__(256) void pack1(const float* __restrict__ hid1,
                                             u16* __restrict__ F1) {
  __shared__ __align__(16) u16 Hs[64 * 72];
  const int b = blockIdx.y, n0 = blockIdx.x << 6, t = threadIdx.x;
  const int r = t >> 2, ds = t & 3;
  const float* hrow = hid1 + ((u64)b * NN + n0 + r) * 64;
#pragma unroll
  for (int c4 = 0; c4 < 4; ++c4) {
    const float4 v = *(const float4*)(hrow + ds * 16 + c4 * 4);
    uint2 p;
    p.x = pk2(v.x, v.y);
    p.y = pk2(v.z, v.w);
    *(uint2*)(Hs + r * 72 + ds * 16 + c4 * 4) = p;
  }
  __syncthreads();
#pragma unroll
  for (int c2 = 0; c2 < 2; ++c2) {
    union { uint4 v; u16 h[8]; } o;
#pragma unroll
    for (int s = 0; s < 8; ++s) o.h[s] = Hs[(ds * 16 + c2 * 8 + s) * 72 + r];
    *(uint4*)(F1 + ((u64)b * 128 + 64 + r) * NN + n0 + ds * 16 + c2 * 8) = o.v;
  }
}

// ---------------------------------------------------------------------------
__global__ __launch_bounds__(256) void candpack(const u16* __restrict__ G, u16* __restrict__ F,
                                                const int DP, const int OFF) {
  const int u = blockIdx.x * 256 + threadIdx.x;
  const int b = u >> 15;
  const int d = (u >> 9) & 63;
  const int seg = (u & 511) << 3;
  union { uint4 v; u16 h[8]; } g, f, o;
  g.v = *(const uint4*)(G + ((u64)b * 128 + d) * NN + seg);
  u16* fp = F + ((u64)b * DP + OFF + d) * NN + seg;
  f.v = *(const uint4*)fp;
#pragma unroll
  for (int s = 0; s < 8; ++s) o.h[s] = f2b(b2f(f.h[s]) * b2f(g.h[s]));
  *(uint4*)fp = o.v;
}

// ---------------------------------------------------------------------------
__global__ __launch_bounds__(256) void hnew_k(const u16* __restrict__ G,
                                              const float* __restrict__ hidL,
                                              u16* __restrict__ HnF,
                                              float* __restrict__ outH) {
  __shared__ __align__(16) float Hs[64 * 72];
  __shared__ __align__(16) float T2[64 * 72];
  const int b = blockIdx.y, n0 = blockIdx.x << 6, t = threadIdx.x;
  const int r = t >> 2, ds = t & 3;
  const float* hrow = hidL + ((u64)b * NN + n0 + r) * 64;
#pragma unroll
  for (int c4 = 0; c4 < 4; ++c4)
    *(float4*)(Hs + r * 72 + ds * 16 + c4 * 4) = *(const float4*)(hrow + ds * 16 + c4 * 4);
  __syncthreads();
#pragma unroll
  for (int c2 = 0; c2 < 2; ++c2) {
    const int ncol = ds * 16 + c2 * 8;
    union { uint4 v; u16 h[8]; } uv, cv, o;
    uv.v = *(const uint4*)(G + ((u64)b * 128 + 64 + r) * NN + n0 + ncol);
    cv.v = *(const uint4*)(G + ((u64)b * 128 + r) * NN + n0 + ncol);
#pragma unroll
    for (int s = 0; s < 8; ++s) {
      const int nl = ncol + s;
      const float uu = b2f(uv.h[s]);
      const float hh = Hs[nl * 72 + r];
      const float cc = b2f(cv.h[s]);
      const float v = uu * hh + (1.f - uu) * cc;
      o.h[s] = f2b(v);
      T2[nl * 72 + r] = v;
    }
    *(uint4*)(HnF + ((u64)b * 128 + r) * NN + n0 + ncol) = o.v;
  }
  __syncthreads();
  const int nl2 = t >> 2, dseg = (t & 3) << 4;
#pragma unroll
  for (int c4 = 0; c4 < 4; ++c4) {
    const float4 v = *(const float4*)(T2 + nl2 * 72 + dseg + c4 * 4);
    *(float4*)(outH + ((u64)b * NN + n0 + nl2) * 64 + dseg + c4 * 4) = v;
  }
}

// ---------------------------------------------------------------------------
__global__ __launch_bounds__(256) void predictk(const float* __restrict__ H1bnd,
                                                const float* __restrict__ Wp,
                                                const float* __restrict__ bp,
                                                float* __restrict__ outp) {
  __shared__ float w[64];
  __shared__ float bb;
  const int t = threadIdx.x;
  if (t < 64) w[t] = Wp[t];
  if (t == 64) bb = bp[0];
  __syncthreads();
  const int idx = blockIdx.x * 256 + t;
  const float* h = H1bnd + (u64)idx * 64;
  float acc = bb;
#pragma unroll
  for (int c4 = 0; c4 < 16; ++c4) {
    const float4 v = *(const float4*)(h + c4 * 4);
    acc += v.x * w[c4 * 4] + v.y * w[c4 * 4 + 1] + v.z * w[c4 * 4 + 2] + v.w * w[c4 * 4 + 3];
  }
  outp[idx] = acc;
}

static inline void launch_gemm(bool big, const float* Af, const u16* Ab,
                               const u16* B, u16* Ct, const u16* Xt,
                               int Cdim, hipStream_t s) {
  if (big) gemm256<<<dim3(16, Cdim >> 8), 512, 0, s>>>(Ab, B, Ct, Xt);
  else     gemm_s<<<dim3(32, Cdim >> 7), 256, 0, s>>>(Af, B, Ct, Xt);
}

extern "C" void kernel_launch(void* const* d_in, const int* in_sizes, int n_in,
                              void* d_out, int out_size, void* d_ws, size_t ws_size,
                              hipStream_t stream) {
  const float* X   = (const float*)d_in[0];
  const float* HID = (const float*)d_in[1];
  const float* Sf  = (const float*)d_in[2];
  const float* Sb  = (const float*)d_in[3];
  const float* Wg0 = (const float*)d_in[4];
  const float* bg0 = (const float*)d_in[5];
  const float* Wc0 = (const float*)d_in[6];
  const float* bc0 = (const float*)d_in[7];
  const float* Wg1 = (const float*)d_in[8];
  const float* bg1 = (const float*)d_in[9];
  const float* Wc1 = (const float*)d_in[10];
  const float* bc1 = (const float*)d_in[11];
  const float* Wp  = (const float*)d_in[12];
  const float* bp  = (const float*)d_in[13];
  float* OUT = (float*)d_out;
  char* ws = (char*)d_ws;

  u16* F = (u16*)(ws);
  u16* G = (u16*)(ws + 167772160ull);
  const u64 NEED_BIG = 167772160ull + 33554432ull + 2ull * 33554432ull + 393216ull;
  const bool big = ws_size >= NEED_BIG;
  u16* Sfb = (u16*)(ws + 167772160ull + 33554432ull);
  u16* Sbb = Sfb + (u64)NN * NN;
  u16* WT = big ? (Sbb + (u64)NN * NN)
                : (u16*)(ws + 167772160ull + 33554432ull);
  u16* Wg0t = WT;                   // 128 x 384
  u16* Wc0t = Wg0t + 128 * 384;     // 64 x 384
  u16* Wg1t = Wc0t + 64 * 384;      // 128 x 640
  u16* Wc1t = Wg1t + 128 * 640;     // 64 x 640

  const float* HID1 = HID + (u64)32 * 4096 * 64;
  float* OUT_H0 = OUT + 131072;
  float* OUT_H1 = OUT + 131072 + 8388608;

  // zero the layer-0 K-padding region of F (rows 11520..13823), read by proj i=5
  hipMemsetAsync(ws + (u64)11520 * NN * 2, 0, (u64)2304 * NN * 2, stream);

  if (big) {
    cvtS<<<8192, 256, 0, stream>>>(Sf, Sfb);
    cvtS<<<8192, 256, 0, stream>>>(Sb, Sbb);
  }

  repackW<<<(128 * 384 + 255) / 256, 256, 0, stream>>>(Wg0, Wg0t, 65, 72, 384, 128);
  repackW<<<(64 * 384 + 255) / 256, 256, 0, stream>>>(Wc0, Wc0t, 65, 72, 384, 64);
  repackW<<<(128 * 640 + 255) / 256, 256, 0, stream>>>(Wg1, Wg1t, 128, 128, 640, 128);
  repackW<<<(64 * 640 + 255) / 256, 256, 0, stream>>>(Wc1, Wc1t, 128, 128, 640, 64);

  // ---------------- layer 0 (Dp=72, C=2304) ----------------
  pack0<<<dim3(64, 32), 256, 0, stream>>>(X, HID, F);
  const u64 R0 = (u64)2304 * NN;
  const dim3 gh(32, 9, 2);
  if (big) {
    // pair 1: {Sf*F -> F+R0, Sb*F -> F+3R0}
    gemm_h<<<gh, 512, 0, stream>>>(Sfb, Sbb, F, F, F + R0, F + 3 * R0, nullptr);
    // pair 2: {Sf*(F+R0) -> F+2R0, Sb*(F+3R0) -> F+4R0}, Xt=F
    gemm_h<<<gh, 512, 0, stream>>>(Sfb, Sbb, F + R0, F + 3 * R0, F + 2 * R0, F + 4 * R0, F);
  } else {
    launch_gemm(big, Sf, Sfb, F, F + R0, nullptr, 2304, stream);
    launch_gemm(big, Sb, Sbb, F, F + 3 * R0, nullptr, 2304, stream);
    launch_gemm(big, Sf, Sfb, F + R0, F + 2 * R0, F, 2304, stream);
    launch_gemm(big, Sb, Sbb, F + 3 * R0, F + 4 * R0, F, 2304, stream);
  }
  proj_k<72, 384><<<dim3(32, 2, 32), 256, 0, stream>>>(Wg0t, F, bg0, G, 128, 0);
  candpack<<<4096, 256, 0, stream>>>(G, F, 72, 1);
  if (big) {
    gemm_h<<<gh, 512, 0, stream>>>(Sfb, Sbb, F, F, F + R0, F + 3 * R0, nullptr);
    gemm_h<<<gh, 512, 0, stream>>>(Sfb, Sbb, F + R0, F + 3 * R0, F + 2 * R0, F + 4 * R0, F);
  } else {
    launch_gemm(big, Sf, Sfb, F, F + R0, nullptr, 2304, stream);
    launch_gemm(big, Sb, Sbb, F, F + 3 * R0, nullptr, 2304, stream);
    launch_gemm(big, Sf, Sfb, F + R0, F + 2 * R0, F, 2304, stream);
    launch_gemm(big, Sb, Sbb, F + 3 * R0, F + 4 * R0, F, 2304, stream);
  }
  proj_k<72, 384><<<dim3(32, 1, 32), 256, 0, stream>>>(Wc0t, F, bc0, G, 128, 1);
  hnew_k<<<dim3(64, 32), 256, 0, stream>>>(G, HID, F, OUT_H0);

  // ---------------- layer 1 (Dp=128, C=4096) ----------------
  pack1<<<dim3(64, 32), 256, 0, stream>>>(HID1, F);
  const u64 R1 = (u64)4096 * NN;
  launch_gemm(big, Sf, Sfb, F, F + R1, nullptr, 4096, stream);
  launch_gemm(big, Sb, Sbb, F, F + 3 * R1, nullptr, 4096, stream);
  launch_gemm(big, Sf, Sfb, F + R1, F + 2 * R1, F, 4096, stream);
  launch_gemm(big, Sb, Sbb, F + 3 * R1, F + 4 * R1, F, 4096, stream);
  proj_k<128, 640><<<dim3(32, 2, 32), 256, 0, stream>>>(Wg1t, F, bg1, G, 128, 0);
  candpack<<<4096, 256, 0, stream>>>(G, F, 128, 64);
  launch_gemm(big, Sf, Sfb, F, F + R1, nullptr, 4096, stream);
  launch_gemm(big, Sb, Sbb, F, F + 3 * R1, nullptr, 4096, stream);
  launch_gemm(big, Sf, Sfb, F + R1, F + 2 * R1, F, 4096, stream);
  launch_gemm(big, Sb, Sbb, F + 3 * R1, F + 4 * R1, F, 4096, stream);
  proj_k<128, 640><<<dim3(32, 1, 32), 256, 0, stream>>>(Wc1t, F, bc1, G, 128, 1);
  hnew_k<<<dim3(64, 32), 256, 0, stream>>>(G, HID1, F, OUT_H1);

  predictk<<<512, 256, 0, stream>>>(OUT_H1, Wp, bp, OUT);
}

// Round 6
// 1875.473 us; speedup vs baseline: 1.3098x; 1.0964x over previous
//
#include <hip/hip_runtime.h>

typedef unsigned short u16;
typedef unsigned int u32;
typedef unsigned long long u64;
typedef short v8s __attribute__((ext_vector_type(8)));
typedef float v4f __attribute__((ext_vector_type(4)));

#define NN 4096
#define BATCH 32

__device__ __forceinline__ float b2f(u16 u) {
  union { u32 i; float f; } c; c.i = ((u32)u) << 16; return c.f;
}
__device__ __forceinline__ u16 f2b(float f) {
  union { float f; u32 i; } c; c.f = f;
  u32 x = c.i;
  return (u16)((x + 0x7fffu + ((x >> 16) & 1u)) >> 16);
}
__device__ __forceinline__ u32 pk2(float a, float b) {
  return (u32)f2b(a) | ((u32)f2b(b) << 16);
}

typedef const __attribute__((address_space(1))) u32* gp_t;
typedef __attribute__((address_space(3))) u32* lp_t;
__device__ __forceinline__ void gld16(const u16* g, u16* l) {
  __builtin_amdgcn_global_load_lds((gp_t)g, (lp_t)l, 16, 0, 0);
}

#define CBAR() asm volatile("" ::: "memory")
#define BARRIER() do { CBAR(); __builtin_amdgcn_s_barrier(); CBAR(); } while (0)
#define LGKM0() asm volatile("s_waitcnt lgkmcnt(0)" ::: "memory")
#define VMC4() asm volatile("s_waitcnt vmcnt(4)" ::: "memory")
#define VMC3() asm volatile("s_waitcnt vmcnt(3)" ::: "memory")
#define VMC0() asm volatile("s_waitcnt vmcnt(0)" ::: "memory")

// ---------------------------------------------------------------------------
// cvtS: f32 -> bf16 (RNE), 8 elems/thread. grid: 8192 x 256 for 16.8M elems.
// ---------------------------------------------------------------------------
__global__ __launch_bounds__(256) void cvtS(const float* __restrict__ S,
                                            u16* __restrict__ Sb) {
  const u64 idx = ((u64)blockIdx.x * 256 + threadIdx.x) * 8;
  const float4 a = *(const float4*)(S + idx);
  const float4 b = *(const float4*)(S + idx + 4);
  uint4 o;
  o.x = pk2(a.x, a.y); o.y = pk2(a.z, a.w);
  o.z = pk2(b.x, b.y); o.w = pk2(b.z, b.w);
  *(uint4*)(Sb + idx) = o;
}

// ---------------------------------------------------------------------------
// gemm256 (R3, verified 103.7us): 256x256 tile, BK=64, 8 waves (2Mx4N).
// Minimal-barrier free-run schedule + one-cluster-ahead operand pipelining.
// grid (16, C/256), block 512.
// ---------------------------------------------------------------------------
__global__ __launch_bounds__(512, 2) void gemm256(const u16* __restrict__ A,
                                                  const u16* __restrict__ B,
                                                  u16* __restrict__ Ct,
                                                  const u16* __restrict__ Xt) {
  // 128 KiB: buf b at b*32768 (u16); regions A-h0 0 | A-h1 8192 | B-h0 16384 | B-h1 24576
  __shared__ __align__(16) u16 lds[65536];
  const int t = threadIdx.x;
  const int wave = t >> 6, lane = t & 63;
  const int q = lane >> 4, r16 = lane & 15;
  const int wm = wave >> 2, wn = wave & 3;

  const int nwg = (int)(gridDim.x * gridDim.y);
  const int bid = (int)(blockIdx.y * gridDim.x + blockIdx.x);
  const int swz = (bid & 7) * (nwg >> 3) + (bid >> 3);
  const int m0 = (swz & 15) << 8;   // gridDim.x == 16 always
  const int c0 = (swz >> 4) << 8;

  v4f acc[8][4];
  const v4f vz = {0.f, 0.f, 0.f, 0.f};
#pragma unroll
  for (int i = 0; i < 8; ++i)
#pragma unroll
    for (int j = 0; j < 4; ++j) acc[i][j] = vz;

  const int srow = t >> 3;
  const int sslot = ((t & 7) ^ (srow & 7)) << 3;      // element col offset
  const u16* pA = A + (u64)(m0 + srow) * NN + sslot;
  const u16* pB = B + (u64)(c0 + srow) * NN + sslot;
  const u64 rstep = (u64)64 * NN;
  const u64 hstep = (u64)128 * NN;
  u16* lw = lds + (wave << 9);

  const int sw8 = (q ^ (r16 & 7)) << 3;
  const int aBase = (wm << 13) + (r16 << 6) + sw8;
  const int bBase = 16384 + ((wn >> 1) << 13) + ((wn & 1) << 12) + (r16 << 6) + sw8;

  const int NT = NN >> 6;  // 64 K-tiles

  gld16(pA, lw);
  gld16(pA + rstep, lw + 4096);
  gld16(pA + hstep, lw + 8192);
  gld16(pA + hstep + rstep, lw + 12288);
  gld16(pB, lw + 16384);
  gld16(pB + rstep, lw + 20480);
  gld16(pB + hstep, lw + 24576);
  gld16(pB + hstep + rstep, lw + 28672);
  gld16(pB + 64, lw + 32768 + 16384);
  gld16(pB + 64 + rstep, lw + 32768 + 20480);
  gld16(pB + 64 + hstep, lw + 32768 + 24576);
  gld16(pB + 64 + hstep + rstep, lw + 32768 + 28672);
  VMC4();
  BARRIER();

  v8s af[4][2], bf01[2][2], bf23[2][2];
#pragma unroll
  for (int i = 0; i < 4; ++i) {
    const int a = aBase + (i << 10);
    af[i][0] = *(const v8s*)(lds + a);
    af[i][1] = *(const v8s*)(lds + (a ^ 32));
  }
#pragma unroll
  for (int j = 0; j < 2; ++j) {
    const int b = bBase + (j << 10);
    bf01[j][0] = *(const v8s*)(lds + b);
    bf01[j][1] = *(const v8s*)(lds + (b ^ 32));
  }

#pragma unroll 2
  for (int T = 0; T < NT; ++T) {
    const int bo = (T & 1) << 15;
    const int no = bo ^ 32768;
    const u64 ka = (u64)(T + 1 < NT ? T + 1 : NT - 1) << 6;
    const u64 kb = (u64)(T + 2 < NT ? T + 2 : NT - 1) << 6;

    // ---- phase 0
    gld16(pA + ka, lw + no);
    gld16(pA + ka + rstep, lw + no + 4096);
#pragma unroll
    for (int j = 0; j < 2; ++j) {
      const int b = bo + bBase + ((2 + j) << 10);
      bf23[j][0] = *(const v8s*)(lds + b);
      bf23[j][1] = *(const v8s*)(lds + (b ^ 32));
    }
    __builtin_amdgcn_s_setprio(1);
#pragma unroll
    for (int i = 0; i < 4; ++i)
#pragma unroll
      for (int j = 0; j < 2; ++j) {
        acc[i][j] = __builtin_amdgcn_mfma_f32_16x16x32_bf16(af[i][0], bf01[j][0], acc[i][j], 0, 0, 0);
        acc[i][j] = __builtin_amdgcn_mfma_f32_16x16x32_bf16(af[i][1], bf01[j][1], acc[i][j], 0, 0, 0);
      }
    __builtin_amdgcn_s_setprio(0);

    // ---- phase 1
    gld16(pA + hstep + ka, lw + no + 8192);
    gld16(pA + hstep + ka + rstep, lw + no + 12288);
    LGKM0();
    BARRIER();
    __builtin_amdgcn_s_setprio(1);
#pragma unroll
    for (int i = 0; i < 4; ++i)
#pragma unroll
      for (int j = 0; j < 2; ++j) {
        acc[i][2 + j] = __builtin_amdgcn_mfma_f32_16x16x32_bf16(af[i][0], bf23[j][0], acc[i][2 + j], 0, 0, 0);
        acc[i][2 + j] = __builtin_amdgcn_mfma_f32_16x16x32_bf16(af[i][1], bf23[j][1], acc[i][2 + j], 0, 0, 0);
      }
    __builtin_amdgcn_s_setprio(0);
#pragma unroll
    for (int i = 0; i < 4; ++i) {
      const int a = bo + aBase + ((4 + i) << 10);
      af[i][0] = *(const v8s*)(lds + a);
      af[i][1] = *(const v8s*)(lds + (a ^ 32));
    }
    __builtin_amdgcn_sched_barrier(0);

    // ---- phase 2
    gld16(pB + kb, lw + bo + 16384);
    gld16(pB + kb + rstep, lw + bo + 20480);
    __builtin_amdgcn_s_setprio(1);
#pragma unroll
    for (int i = 0; i < 4; ++i)
#pragma unroll
      for (int j = 0; j < 2; ++j) {
        acc[4 + i][2 + j] = __builtin_amdgcn_mfma_f32_16x16x32_bf16(af[i][0], bf23[j][0], acc[4 + i][2 + j], 0, 0, 0);
        acc[4 + i][2 + j] = __builtin_amdgcn_mfma_f32_16x16x32_bf16(af[i][1], bf23[j][1], acc[4 + i][2 + j], 0, 0, 0);
      }
    __builtin_amdgcn_s_setprio(0);

    // ---- phase 3
    gld16(pB + hstep + kb, lw + bo + 24576);
    gld16(pB + hstep + kb + rstep, lw + bo + 28672);
    VMC4();
    BARRIER();
    __builtin_amdgcn_s_setprio(1);
#pragma unroll
    for (int i = 0; i < 4; ++i)
#pragma unroll
      for (int j = 0; j < 2; ++j) {
        acc[4 + i][j] = __builtin_amdgcn_mfma_f32_16x16x32_bf16(af[i][0], bf01[j][0], acc[4 + i][j], 0, 0, 0);
        acc[4 + i][j] = __builtin_amdgcn_mfma_f32_16x16x32_bf16(af[i][1], bf01[j][1], acc[4 + i][j], 0, 0, 0);
      }
    __builtin_amdgcn_s_setprio(0);
#pragma unroll
    for (int i = 0; i < 4; ++i) {
      const int a = no + aBase + (i << 10);
      af[i][0] = *(const v8s*)(lds + a);
      af[i][1] = *(const v8s*)(lds + (a ^ 32));
    }
#pragma unroll
    for (int j = 0; j < 2; ++j) {
      const int b = no + bBase + (j << 10);
      bf01[j][0] = *(const v8s*)(lds + b);
      bf01[j][1] = *(const v8s*)(lds + (b ^ 32));
    }
    __builtin_amdgcn_sched_barrier(0);
  }

  // ---------------- epilogue ----------------
  VMC0();
  __syncthreads();
#pragma unroll
  for (int i = 0; i < 8; ++i)
#pragma unroll
    for (int j = 0; j < 4; ++j) {
      const int cl = (wn << 6) + (j << 4) + r16;
      const int ml = (wm << 7) + (i << 4) + (q << 2);
      const int phys = (cl << 8) + ((((ml >> 3) ^ (cl & 7)) << 3) | (ml & 7));
      uint2 pv;
      pv.x = pk2(acc[i][j][0], acc[i][j][1]);
      pv.y = pk2(acc[i][j][2], acc[i][j][3]);
      *(uint2*)(lds + phys) = pv;
    }
  __syncthreads();
#pragma unroll
  for (int it = 0; it < 16; ++it) {
    const int f = (it << 9) + t;
    const int cl = f >> 5, sl = f & 31;
    const int phys = (cl << 8) + ((sl ^ (cl & 7)) << 3);
    union { uint4 v; u16 e[8]; } tv;
    tv.v = *(const uint4*)(lds + phys);
    const u64 gi = (u64)(c0 + cl) * NN + m0 + (sl << 3);
    if (Xt) {
      union { uint4 v; u16 e[8]; } xv, ov;
      xv.v = *(const uint4*)(Xt + gi);
#pragma unroll
      for (int s = 0; s < 8; ++s) ov.e[s] = f2b(2.f * b2f(tv.e[s]) - b2f(xv.e[s]));
      *(uint4*)(Ct + gi) = ov.v;
    } else {
      *(uint4*)(Ct + gi) = tv.v;
    }
  }
}

// ---------------------------------------------------------------------------
// gemm192: 256x192 tile for layer-0 (C=2304 -> 16x12 = 192 blocks, one full
// round of <=256 CUs with 0.75-size blocks). Same BK=64, 8 waves (2Mx4N,
// per-wave 128x48, acc[8][3]), same 2-barrier free-run schedule and hazard
// structure as gemm256; A staged as 4 ops, B as 3 ops, vmcnt(3) leaves
// B(T+2)'s 3 ops in flight. grid (16, 12), block 512.
// ---------------------------------------------------------------------------
__global__ __launch_bounds__(512, 2) void gemm192(const u16* __restrict__ A,
                                                  const u16* __restrict__ B,
                                                  u16* __restrict__ Ct,
                                                  const u16* __restrict__ Xt) {
  // 2 bufs x 28672 u16: A [256][64] at 0 | B [192][64] at 16384
  __shared__ __align__(16) u16 lds[57344];
  const int t = threadIdx.x;
  const int wave = t >> 6, lane = t & 63;
  const int q = lane >> 4, r16 = lane & 15;
  const int wm = wave >> 2, wn = wave & 3;

  const int nwg = (int)(gridDim.x * gridDim.y);   // 192, % 8 == 0
  const int bid = (int)(blockIdx.y * gridDim.x + blockIdx.x);
  const int swz = (bid & 7) * (nwg >> 3) + (bid >> 3);
  const int m0 = (swz & 15) << 8;                 // gridDim.x == 16
  const int c0 = (swz >> 4) * 192;                // 0..11

  v4f acc[8][3];
  const v4f vz = {0.f, 0.f, 0.f, 0.f};
#pragma unroll
  for (int i = 0; i < 8; ++i)
#pragma unroll
    for (int j = 0; j < 3; ++j) acc[i][j] = vz;

  const int srow = t >> 3;
  const int sslot = ((t & 7) ^ (srow & 7)) << 3;
  const u16* pA = A + (u64)(m0 + srow) * NN + sslot;
  const u16* pB = B + (u64)(c0 + srow) * NN + sslot;
  const u64 rstep = (u64)64 * NN;
  u16* lw = lds + (wave << 9);

  const int sw8 = (q ^ (r16 & 7)) << 3;
  const int aBase = (wm << 13) + (r16 << 6) + sw8;               // + i<<10
  const int bBase = 16384 + wn * 3072 + (r16 << 6) + sw8;        // + j<<10

  const int NT = NN >> 6;  // 64 K-tiles

  // prologue: A(0) 4 ops, B(0) 3 ops, B(1) 3 ops; VMC3 leaves B(1) in flight
  gld16(pA, lw);
  gld16(pA + rstep, lw + 4096);
  gld16(pA + 2 * rstep, lw + 8192);
  gld16(pA + 3 * rstep, lw + 12288);
  gld16(pB, lw + 16384);
  gld16(pB + rstep, lw + 20480);
  gld16(pB + 2 * rstep, lw + 24576);
  gld16(pB + 64, lw + 28672 + 16384);
  gld16(pB + 64 + rstep, lw + 28672 + 20480);
  gld16(pB + 64 + 2 * rstep, lw + 28672 + 24576);
  VMC3();
  BARRIER();

  v8s af[4][2], bf01[2][2], bf2[2];
#pragma unroll
  for (int i = 0; i < 4; ++i) {
    const int a = aBase + (i << 10);
    af[i][0] = *(const v8s*)(lds + a);
    af[i][1] = *(const v8s*)(lds + (a ^ 32));
  }
#pragma unroll
  for (int j = 0; j < 2; ++j) {
    const int b = bBase + (j << 10);
    bf01[j][0] = *(const v8s*)(lds + b);
    bf01[j][1] = *(const v8s*)(lds + (b ^ 32));
  }

#pragma unroll 2
  for (int T = 0; T < NT; ++T) {
    const int bo = (T & 1) ? 28672 : 0;
    const int no = bo ^ 28672;
    const u64 ka = (u64)(T + 1 < NT ? T + 1 : NT - 1) << 6;
    const u64 kb = (u64)(T + 2 < NT ? T + 2 : NT - 1) << 6;

    // ---- P0: stage A-h0(T+1) | read bf2 | MFMA af03 x bf01 (16)
    gld16(pA + ka, lw + no);
    gld16(pA + ka + rstep, lw + no + 4096);
    {
      const int b = bo + bBase + 2048;   // j = 2
      bf2[0] = *(const v8s*)(lds + b);
      bf2[1] = *(const v8s*)(lds + (b ^ 32));
    }
    __builtin_amdgcn_s_setprio(1);
#pragma unroll
    for (int i = 0; i < 4; ++i)
#pragma unroll
      for (int j = 0; j < 2; ++j) {
        acc[i][j] = __builtin_amdgcn_mfma_f32_16x16x32_bf16(af[i][0], bf01[j][0], acc[i][j], 0, 0, 0);
        acc[i][j] = __builtin_amdgcn_mfma_f32_16x16x32_bf16(af[i][1], bf01[j][1], acc[i][j], 0, 0, 0);
      }
    __builtin_amdgcn_s_setprio(0);

    // ---- P1: stage A-h1(T+1) | LGKM0 + BARRIER (B-region WAR) |
    //          MFMA af03 x bf2 (8) | read af47
    gld16(pA + ka + 2 * rstep, lw + no + 8192);
    gld16(pA + ka + 3 * rstep, lw + no + 12288);
    LGKM0();
    BARRIER();
    __builtin_amdgcn_s_setprio(1);
#pragma unroll
    for (int i = 0; i < 4; ++i) {
      acc[i][2] = __builtin_amdgcn_mfma_f32_16x16x32_bf16(af[i][0], bf2[0], acc[i][2], 0, 0, 0);
      acc[i][2] = __builtin_amdgcn_mfma_f32_16x16x32_bf16(af[i][1], bf2[1], acc[i][2], 0, 0, 0);
    }
    __builtin_amdgcn_s_setprio(0);
#pragma unroll
    for (int i = 0; i < 4; ++i) {
      const int a = bo + aBase + ((4 + i) << 10);
      af[i][0] = *(const v8s*)(lds + a);
      af[i][1] = *(const v8s*)(lds + (a ^ 32));
    }
    __builtin_amdgcn_sched_barrier(0);

    // ---- P2: stage B-r01(T+2) | MFMA af47 x bf2 (8)
    gld16(pB + kb, lw + bo + 16384);
    gld16(pB + kb + rstep, lw + bo + 20480);
    __builtin_amdgcn_s_setprio(1);
#pragma unroll
    for (int i = 0; i < 4; ++i) {
      acc[4 + i][2] = __builtin_amdgcn_mfma_f32_16x16x32_bf16(af[i][0], bf2[0], acc[4 + i][2], 0, 0, 0);
      acc[4 + i][2] = __builtin_amdgcn_mfma_f32_16x16x32_bf16(af[i][1], bf2[1], acc[4 + i][2], 0, 0, 0);
    }
    __builtin_amdgcn_s_setprio(0);

    // ---- P3: stage B-r2(T+2) | MFMA af47 x bf01 (16) | VMC3 + BARRIER | prefetch
    gld16(pB + kb + 2 * rstep, lw + bo + 24576);
    __builtin_amdgcn_s_setprio(1);
#pragma unroll
    for (int i = 0; i < 4; ++i)
#pragma unroll
      for (int j = 0; j < 2; ++j) {
        acc[4 + i][j] = __builtin_amdgcn_mfma_f32_16x16x32_bf16(af[i][0], bf01[j][0], acc[4 + i][j], 0, 0, 0);
        acc[4 + i][j] = __builtin_amdgcn_mfma_f32_16x16x32_bf16(af[i][1], bf01[j][1], acc[4 + i][j], 0, 0, 0);
      }
    __builtin_amdgcn_s_setprio(0);
    VMC3();   // drains A(T+1) (and all earlier); leaves B(T+2)'s 3 ops in flight
    BARRIER();
#pragma unroll
    for (int i = 0; i < 4; ++i) {
      const int a = no + aBase + (i << 10);
      af[i][0] = *(const v8s*)(lds + a);
      af[i][1] = *(const v8s*)(lds + (a ^ 32));
    }
#pragma unroll
    for (int j = 0; j < 2; ++j) {
      const int b = no + bBase + (j << 10);
      bf01[j][0] = *(const v8s*)(lds + b);
      bf01[j][1] = *(const v8s*)(lds + (b ^ 32));
    }
    __builtin_amdgcn_sched_barrier(0);
  }

  // ---------------- epilogue: 192c x 256m through LDS ----------------
  VMC0();
  __syncthreads();
#pragma unroll
  for (int i = 0; i < 8; ++i)
#pragma unroll
    for (int j = 0; j < 3; ++j) {
      const int cl = wn * 48 + j * 16 + r16;                 // 0..191
      const int ml = (wm << 7) + (i << 4) + (q << 2);        // 0..255
      const int phys = (cl << 8) + ((((ml >> 3) ^ (cl & 7)) << 3) | (ml & 7));
      uint2 pv;
      pv.x = pk2(acc[i][j][0], acc[i][j][1]);
      pv.y = pk2(acc[i][j][2], acc[i][j][3]);
      *(uint2*)(lds + phys) = pv;
    }
  __syncthreads();
#pragma unroll
  for (int it = 0; it < 12; ++it) {
    const int f = (it << 9) + t;
    const int cl = f >> 5, sl = f & 31;
    const int phys = (cl << 8) + ((sl ^ (cl & 7)) << 3);
    union { uint4 v; u16 e[8]; } tv;
    tv.v = *(const uint4*)(lds + phys);
    const u64 gi = (u64)(c0 + cl) * NN + m0 + (sl << 3);
    if (Xt) {
      union { uint4 v; u16 e[8]; } xv, ov;
      xv.v = *(const uint4*)(Xt + gi);
#pragma unroll
      for (int s = 0; s < 8; ++s) ov.e[s] = f2b(2.f * b2f(tv.e[s]) - b2f(xv.e[s]));
      *(uint4*)(Ct + gi) = ov.v;
    } else {
      *(uint4*)(Ct + gi) = tv.v;
    }
  }
}

// ---------------------------------------------------------------------------
// gemm_s (fallback if workspace too small for bf16 S): A f32, in-loop cvt.
// ---------------------------------------------------------------------------
__global__ __launch_bounds__(256) void gemm_s(const float* __restrict__ A,
                                              const u16* __restrict__ B,
                                              u16* __restrict__ Ct,
                                              const u16* __restrict__ Xt) {
  __shared__ __align__(16) u16 As[4096];
  __shared__ __align__(16) u16 Bs[4096];
  __shared__ __align__(16) u16 T[16384];
  const int t = threadIdx.x;
  const int wave = t >> 6, lane = t & 63;
  const int m0 = blockIdx.x << 7, c0 = blockIdx.y << 7;
  const int wm = (wave >> 1) << 6, wc = (wave & 1) << 6;
  const int q = lane >> 4, r16 = lane & 15;
  v4f acc[4][4];
  const v4f vz = {0.f, 0.f, 0.f, 0.f};
#pragma unroll
  for (int i = 0; i < 4; ++i)
#pragma unroll
    for (int j = 0; j < 4; ++j) acc[i][j] = vz;

  const int sr = t >> 2;
  const int sc = (t & 3) << 3;
  const u64 abase = (u64)(m0 + sr) * NN + sc;
  const u64 bbase = (u64)(c0 + sr) * NN + sc;
  const u64 rstep = (u64)64 * NN;
  u16* as0 = As + sr * 32 + sc;
  u16* as1 = As + (64 + sr) * 32 + sc;
  u16* bs0 = Bs + sr * 32 + sc;
  u16* bs1 = Bs + (64 + sr) * 32 + sc;

  for (int k0 = 0; k0 < NN; k0 += 32) {
    const float4 a0l = *(const float4*)(A + abase + k0);
    const float4 a0h = *(const float4*)(A + abase + k0 + 4);
    const float4 a1l = *(const float4*)(A + abase + rstep + k0);
    const float4 a1h = *(const float4*)(A + abase + rstep + k0 + 4);
    const uint4 b0 = *(const uint4*)(B + bbase + k0);
    const uint4 b1 = *(const uint4*)(B + bbase + rstep + k0);
    uint4 pa0, pa1;
    pa0.x = pk2(a0l.x, a0l.y); pa0.y = pk2(a0l.z, a0l.w);
    pa0.z = pk2(a0h.x, a0h.y); pa0.w = pk2(a0h.z, a0h.w);
    pa1.x = pk2(a1l.x, a1l.y); pa1.y = pk2(a1l.z, a1l.w);
    pa1.z = pk2(a1h.x, a1h.y); pa1.w = pk2(a1h.z, a1h.w);
    __syncthreads();
    *(uint4*)as0 = pa0;
    *(uint4*)as1 = pa1;
    *(uint4*)bs0 = b0;
    *(uint4*)bs1 = b1;
    __syncthreads();
    v8s af[4], bf[4];
#pragma unroll
    for (int i = 0; i < 4; ++i)
      af[i] = *(const v8s*)(As + ((wm + i * 16 + r16) << 5) + (q << 3));
#pragma unroll
    for (int j = 0; j < 4; ++j)
      bf[j] = *(const v8s*)(Bs + ((wc + j * 16 + r16) << 5) + (q << 3));
#pragma unroll
    for (int i = 0; i < 4; ++i)
#pragma unroll
      for (int j = 0; j < 4; ++j)
        acc[i][j] = __builtin_amdgcn_mfma_f32_16x16x32_bf16(af[i], bf[j], acc[i][j], 0, 0, 0);
  }
#pragma unroll
  for (int i = 0; i < 4; ++i)
#pragma unroll
    for (int j = 0; j < 4; ++j) {
      const int cl = wc + j * 16 + r16;
      const int mm = wm + i * 16 + (q << 2);
      uint2 pv;
      pv.x = pk2(acc[i][j][0], acc[i][j][1]);
      pv.y = pk2(acc[i][j][2], acc[i][j][3]);
      *(uint2*)(T + (cl << 7) + mm) = pv;
    }
  __syncthreads();
#pragma unroll
  for (int it = 0; it < 8; ++it) {
    const int flat = it * 256 + t;
    const int cl = flat >> 4;
    const int seg = (flat & 15) << 3;
    const u64 gi = (u64)(c0 + cl) * NN + m0 + seg;
    union { uint4 v; u16 e[8]; } tv;
    tv.v = *(uint4*)(T + (cl << 7) + seg);
    if (Xt) {
      union { uint4 v; u16 e[8]; } xv, ov;
      xv.v = *(const uint4*)(Xt + gi);
#pragma unroll
      for (int s = 0; s < 8; ++s) ov.e[s] = f2b(2.f * b2f(tv.e[s]) - b2f(xv.e[s]));
      *(uint4*)(Ct + gi) = ov.v;
    } else {
      *(uint4*)(Ct + gi) = tv.v;
    }
  }
}

// ---------------------------------------------------------------------------
// Projection: out[b*JSTR + j][n] = act( sum_k Wt[j][k] * F[row(k,b)][n] + b[j] )
// ---------------------------------------------------------------------------
template <int DP, int KTOT>
__global__ __launch_bounds__(256) void proj_k(const u16* __restrict__ Wt,
                                              const u16* __restrict__ F,
                                              const float* __restrict__ bias,
                                              u16* __restrict__ outp,
                                              const int JSTR, const int ACT) {
  __shared__ __align__(16) u16 As2[2048];  // 64 j x 32 k
  __shared__ __align__(16) u16 Bs2[4096];  // 32 k x 128 n
  const int t = threadIdx.x;
  const int wave = t >> 6, lane = t & 63;
  const int q = lane >> 4, r16 = lane & 15;
  const int n0 = blockIdx.x << 7;
  const int j0 = blockIdx.y << 6;
  const int b = blockIdx.z;
  v4f acc[4][2];
  const v4f vz = {0.f, 0.f, 0.f, 0.f};
#pragma unroll
  for (int i = 0; i < 4; ++i) { acc[i][0] = vz; acc[i][1] = vz; }

  const int ar = t >> 2, ac = (t & 3) << 3;
  const u64 wbase = (u64)(j0 + ar) * KTOT + ac;

  for (int k0 = 0; k0 < KTOT; k0 += 32) {
    const uint4 av = *(const uint4*)(Wt + wbase + k0);
    uint4 bv[2];
#pragma unroll
    for (int ci = 0; ci < 2; ++ci) {
      const int c = ci * 256 + t;
      const int kr = c >> 4;
      const int seg = (c & 15) << 3;
      const int kk = k0 + kr;
      const int i = kk / DP;
      const int d = kk - i * DP;
      bv[ci] = *(const uint4*)(F + ((u64)i * (BATCH * DP) + (u64)b * DP + d) * NN + n0 + seg);
    }
    __syncthreads();
    *(uint4*)(As2 + ar * 32 + ac) = av;
#pragma unroll
    for (int ci = 0; ci < 2; ++ci) {
      const int c = ci * 256 + t;
      const int kr = c >> 4;
      const int seg = (c & 15) << 3;
      *(uint4*)(Bs2 + (kr << 7) + seg) = bv[ci];
    }
    __syncthreads();
    v8s af[4], bf[2];
#pragma unroll
    for (int i = 0; i < 4; ++i)
      af[i] = *(const v8s*)(As2 + ((i * 16 + r16) << 5) + (q << 3));
#pragma unroll
    for (int jj = 0; jj < 2; ++jj) {
      const int nn = (wave << 5) + jj * 16 + r16;
      v8s v;
#pragma unroll
      for (int s = 0; s < 8; ++s) v[s] = (short)Bs2[(((q << 3) + s) << 7) + nn];
      bf[jj] = v;
    }
#pragma unroll
    for (int i = 0; i < 4; ++i)
#pragma unroll
      for (int jj = 0; jj < 2; ++jj)
        acc[i][jj] = __builtin_amdgcn_mfma_f32_16x16x32_bf16(af[i], bf[jj], acc[i][jj], 0, 0, 0);
  }
#pragma unroll
  for (int i = 0; i < 4; ++i)
#pragma unroll
    for (int jj = 0; jj < 2; ++jj)
#pragma unroll
      for (int r = 0; r < 4; ++r) {
        const int j = j0 + i * 16 + (q << 2) + r;
        const int n = n0 + (wave << 5) + jj * 16 + r16;
        float v = acc[i][jj][r] + bias[j];
        v = ACT ? (1.f - 2.f / (__expf(2.f * v) + 1.f)) : (1.f / (1.f + __expf(-v)));
        outp[((u64)b * JSTR + j) * NN + n] = f2b(v);
      }
}

// ---------------------------------------------------------------------------
__global__ __launch_bounds__(256) void repackW(const float* __restrict__ W, u16* __restrict__ Wt,
                                               const int D, const int DP, const int KTOT,
                                               const int J) {
  const int idx = blockIdx.x * 256 + threadIdx.x;
  if (idx >= J * KTOT) return;
  const int j = idx / KTOT, k = idx - j * KTOT;
  const int i = k / DP, d = k - i * DP;
  u16 v = 0;
  if (i < 5 && d < D) v = f2b(W[(i * D + d) * J + j]);
  Wt[idx] = v;
}

// ---------------------------------------------------------------------------
__global__ __launch_bounds__(256) void pack0(const float* __restrict__ x,
                                             const float* __restrict__ hid0,
                                             u16* __restrict__ F0) {
  __shared__ __align__(16) u16 Hs[64 * 72];
  const int b = blockIdx.y, n0 = blockIdx.x << 6, t = threadIdx.x;
  const int r = t >> 2, ds = t & 3;
  const float* hrow = hid0 + ((u64)b * NN + n0 + r) * 64;
#pragma unroll
  for (int c4 = 0; c4 < 4; ++c4) {
    const float4 v = *(const float4*)(hrow + ds * 16 + c4 * 4);
    uint2 p;
    p.x = pk2(v.x, v.y);
    p.y = pk2(v.z, v.w);
    *(uint2*)(Hs + r * 72 + ds * 16 + c4 * 4) = p;
  }
  __syncthreads();
#pragma unroll
  for (int c2 = 0; c2 < 2; ++c2) {
    union { uint4 v; u16 h[8]; } o;
#pragma unroll
    for (int s = 0; s < 8; ++s) o.h[s] = Hs[(ds * 16 + c2 * 8 + s) * 72 + r];
    *(uint4*)(F0 + ((u64)b * 72 + 1 + r) * NN + n0 + ds * 16 + c2 * 8) = o.v;
  }
  if (t < 64) {
    F0[(u64)b * 72 * NN + n0 + t] = f2b(x[(u64)b * NN + n0 + t]);
  } else if (t < 120) {
    const int tt = t - 64;
    const int row = 65 + (tt >> 3), seg = (tt & 7) << 3;
    uint4 z; z.x = z.y = z.z = z.w = 0;
    *(uint4*)(F0 + ((u64)b * 72 + row) * NN + n0 + seg) = z;
  }
}

// ---------------------------------------------------------------------------
__global__ __launch_bounds__(256) void pack1(const float* __restrict__ hid1,
                                             u16* __restrict__ F1) {
  __shared__ __align__(16) u16 Hs[64 * 72];
  const int b = blockIdx.y, n0 = blockIdx.x << 6, t = threadIdx.x;
  const int r = t >> 2, ds = t & 3;
  const float* hrow = hid1 + ((u64)b * NN + n0 + r) * 64;
#pragma unroll
  for (int c4 = 0; c4 < 4; ++c4) {
    const float4 v = *(const float4*)(hrow + ds * 16 + c4 * 4);
    uint2 p;
    p.x = pk2(v.x, v.y);
    p.y = pk2(v.z, v.w);
    *(uint2*)(Hs + r * 72 + ds * 16 + c4 * 4) = p;
  }
  __syncthreads();
#pragma unroll
  for (int c2 = 0; c2 < 2; ++c2) {
    union { uint4 v; u16 h[8]; } o;
#pragma unroll
    for (int s = 0; s < 8; ++s) o.h[s] = Hs[(ds * 16 + c2 * 8 + s) * 72 + r];
    *(uint4*)(F1 + ((u64)b * 128 + 64 + r) * NN + n0 + ds * 16 + c2 * 8) = o.v;
  }
}

// ---------------------------------------------------------------------------
__global__ __launch_bounds__(256) void candpack(const u16* __restrict__ G, u16* __restrict__ F,
                                                const int DP, const int OFF) {
  const int u = blockIdx.x * 256 + threadIdx.x;
  const int b = u >> 15;
  const int d = (u >> 9) & 63;
  const int seg = (u & 511) << 3;
  union { uint4 v; u16 h[8]; } g, f, o;
  g.v = *(const uint4*)(G + ((u64)b * 128 + d) * NN + seg);
  u16* fp = F + ((u64)b * DP + OFF + d) * NN + seg;
  f.v = *(const uint4*)fp;
#pragma unroll
  for (int s = 0; s < 8; ++s) o.h[s] = f2b(b2f(f.h[s]) * b2f(g.h[s]));
  *(uint4*)fp = o.v;
}

// ---------------------------------------------------------------------------
__global__ __launch_bounds__(256) void hnew_k(const u16* __restrict__ G,
                                              const float* __restrict__ hidL,
                                              u16* __restrict__ HnF,
                                              float* __restrict__ outH) {
  __shared__ __align__(16) float Hs[64 * 72];
  __shared__ __align__(16) float T2[64 * 72];
  const int b = blockIdx.y, n0 = blockIdx.x << 6, t = threadIdx.x;
  const int r = t >> 2, ds = t & 3;
  const float* hrow = hidL + ((u64)b * NN + n0 + r) * 64;
#pragma unroll
  for (int c4 = 0; c4 < 4; ++c4)
    *(float4*)(Hs + r * 72 + ds * 16 + c4 * 4) = *(const float4*)(hrow + ds * 16 + c4 * 4);
  __syncthreads();
#pragma unroll
  for (int c2 = 0; c2 < 2; ++c2) {
    const int ncol = ds * 16 + c2 * 8;
    union { uint4 v; u16 h[8]; } uv, cv, o;
    uv.v = *(const uint4*)(G + ((u64)b * 128 + 64 + r) * NN + n0 + ncol);
    cv.v = *(const uint4*)(G + ((u64)b * 128 + r) * NN + n0 + ncol);
#pragma unroll
    for (int s = 0; s < 8; ++s) {
      const int nl = ncol + s;
      const float uu = b2f(uv.h[s]);
      const float hh = Hs[nl * 72 + r];
      const float cc = b2f(cv.h[s]);
      const float v = uu * hh + (1.f - uu) * cc;
      o.h[s] = f2b(v);
      T2[nl * 72 + r] = v;
    }
    *(uint4*)(HnF + ((u64)b * 128 + r) * NN + n0 + ncol) = o.v;
  }
  __syncthreads();
  const int nl2 = t >> 2, dseg = (t & 3) << 4;
#pragma unroll
  for (int c4 = 0; c4 < 4; ++c4) {
    const float4 v = *(const float4*)(T2 + nl2 * 72 + dseg + c4 * 4);
    *(float4*)(outH + ((u64)b * NN + n0 + nl2) * 64 + dseg + c4 * 4) = v;
  }
}

// ---------------------------------------------------------------------------
__global__ __launch_bounds__(256) void predictk(const float* __restrict__ H1bnd,
                                                const float* __restrict__ Wp,
                                                const float* __restrict__ bp,
                                                float* __restrict__ outp) {
  __shared__ float w[64];
  __shared__ float bb;
  const int t = threadIdx.x;
  if (t < 64) w[t] = Wp[t];
  if (t == 64) bb = bp[0];
  __syncthreads();
  const int idx = blockIdx.x * 256 + t;
  const float* h = H1bnd + (u64)idx * 64;
  float acc = bb;
#pragma unroll
  for (int c4 = 0; c4 < 16; ++c4) {
    const float4 v = *(const float4*)(h + c4 * 4);
    acc += v.x * w[c4 * 4] + v.y * w[c4 * 4 + 1] + v.z * w[c4 * 4 + 2] + v.w * w[c4 * 4 + 3];
  }
  outp[idx] = acc;
}

extern "C" void kernel_launch(void* const* d_in, const int* in_sizes, int n_in,
                              void* d_out, int out_size, void* d_ws, size_t ws_size,
                              hipStream_t stream) {
  const float* X   = (const float*)d_in[0];
  const float* HID = (const float*)d_in[1];
  const float* Sf  = (const float*)d_in[2];
  const float* Sb  = (const float*)d_in[3];
  const float* Wg0 = (const float*)d_in[4];
  const float* bg0 = (const float*)d_in[5];
  const float* Wc0 = (const float*)d_in[6];
  const float* bc0 = (const float*)d_in[7];
  const float* Wg1 = (const float*)d_in[8];
  const float* bg1 = (const float*)d_in[9];
  const float* Wc1 = (const float*)d_in[10];
  const float* bc1 = (const float*)d_in[11];
  const float* Wp  = (const float*)d_in[12];
  const float* bp  = (const float*)d_in[13];
  float* OUT = (float*)d_out;
  char* ws = (char*)d_ws;

  u16* F = (u16*)(ws);
  u16* G = (u16*)(ws + 167772160ull);
  const u64 NEED_BIG = 167772160ull + 33554432ull + 2ull * 33554432ull + 393216ull;
  const bool big = ws_size >= NEED_BIG;
  u16* Sfb = (u16*)(ws + 167772160ull + 33554432ull);
  u16* Sbb = Sfb + (u64)NN * NN;
  u16* WT = big ? (Sbb + (u64)NN * NN)
                : (u16*)(ws + 167772160ull + 33554432ull);
  u16* Wg0t = WT;                   // 128 x 384
  u16* Wc0t = Wg0t + 128 * 384;     // 64 x 384
  u16* Wg1t = Wc0t + 64 * 384;      // 128 x 640
  u16* Wc1t = Wg1t + 128 * 640;     // 64 x 640

  const float* HID1 = HID + (u64)32 * 4096 * 64;
  float* OUT_H0 = OUT + 131072;
  float* OUT_H1 = OUT + 131072 + 8388608;

  // zero the layer-0 K-padding region of F (rows 11520..13823), read by proj i=5
  hipMemsetAsync(ws + (u64)11520 * NN * 2, 0, (u64)2304 * NN * 2, stream);

  if (big) {
    cvtS<<<8192, 256, 0, stream>>>(Sf, Sfb);
    cvtS<<<8192, 256, 0, stream>>>(Sb, Sbb);
  }

  repackW<<<(128 * 384 + 255) / 256, 256, 0, stream>>>(Wg0, Wg0t, 65, 72, 384, 128);
  repackW<<<(64 * 384 + 255) / 256, 256, 0, stream>>>(Wc0, Wc0t, 65, 72, 384, 64);
  repackW<<<(128 * 640 + 255) / 256, 256, 0, stream>>>(Wg1, Wg1t, 128, 128, 640, 128);
  repackW<<<(64 * 640 + 255) / 256, 256, 0, stream>>>(Wc1, Wc1t, 128, 128, 640, 64);

  // ---------------- layer 0 (Dp=72, C=2304) ----------------
  pack0<<<dim3(64, 32), 256, 0, stream>>>(X, HID, F);
  const u64 R0 = (u64)2304 * NN;
  const dim3 g192(16, 12);
  if (big) {
    gemm192<<<g192, 512, 0, stream>>>(Sfb, F, F + R0, nullptr);
    gemm192<<<g192, 512, 0, stream>>>(Sbb, F, F + 3 * R0, nullptr);
    gemm192<<<g192, 512, 0, stream>>>(Sfb, F + R0, F + 2 * R0, F);
    gemm192<<<g192, 512, 0, stream>>>(Sbb, F + 3 * R0, F + 4 * R0, F);
  } else {
    gemm_s<<<dim3(32, 18), 256, 0, stream>>>(Sf, F, F + R0, nullptr);
    gemm_s<<<dim3(32, 18), 256, 0, stream>>>(Sb, F, F + 3 * R0, nullptr);
    gemm_s<<<dim3(32, 18), 256, 0, stream>>>(Sf, F + R0, F + 2 * R0, F);
    gemm_s<<<dim3(32, 18), 256, 0, stream>>>(Sb, F + 3 * R0, F + 4 * R0, F);
  }
  proj_k<72, 384><<<dim3(32, 2, 32), 256, 0, stream>>>(Wg0t, F, bg0, G, 128, 0);
  candpack<<<4096, 256, 0, stream>>>(G, F, 72, 1);
  if (big) {
    gemm192<<<g192, 512, 0, stream>>>(Sfb, F, F + R0, nullptr);
    gemm192<<<g192, 512, 0, stream>>>(Sbb, F, F + 3 * R0, nullptr);
    gemm192<<<g192, 512, 0, stream>>>(Sfb, F + R0, F + 2 * R0, F);
    gemm192<<<g192, 512, 0, stream>>>(Sbb, F + 3 * R0, F + 4 * R0, F);
  } else {
    gemm_s<<<dim3(32, 18), 256, 0, stream>>>(Sf, F, F + R0, nullptr);
    gemm_s<<<dim3(32, 18), 256, 0, stream>>>(Sb, F, F + 3 * R0, nullptr);
    gemm_s<<<dim3(32, 18), 256, 0, stream>>>(Sf, F + R0, F + 2 * R0, F);
    gemm_s<<<dim3(32, 18), 256, 0, stream>>>(Sb, F + 3 * R0, F + 4 * R0, F);
  }
  proj_k<72, 384><<<dim3(32, 1, 32), 256, 0, stream>>>(Wc0t, F, bc0, G, 128, 1);
  hnew_k<<<dim3(64, 32), 256, 0, stream>>>(G, HID, F, OUT_H0);

  // ---------------- layer 1 (Dp=128, C=4096) ----------------
  pack1<<<dim3(64, 32), 256, 0, stream>>>(HID1, F);
  const u64 R1 = (u64)4096 * NN;
  const dim3 g256(16, 16);
  if (big) {
    gemm256<<<g256, 512, 0, stream>>>(Sfb, F, F + R1, nullptr);
    gemm256<<<g256, 512, 0, stream>>>(Sbb, F, F + 3 * R1, nullptr);
    gemm256<<<g256, 512, 0, stream>>>(Sfb, F + R1, F + 2 * R1, F);
    gemm256<<<g256, 512, 0, stream>>>(Sbb, F + 3 * R1, F + 4 * R1, F);
  } else {
    gemm_s<<<dim3(32, 32), 256, 0, stream>>>(Sf, F, F + R1, nullptr);
    gemm_s<<<dim3(32, 32), 256, 0, stream>>>(Sb, F, F + 3 * R1, nullptr);
    gemm_s<<<dim3(32, 32), 256, 0, stream>>>(Sf, F + R1, F + 2 * R1, F);
    gemm_s<<<dim3(32, 32), 256, 0, stream>>>(Sb, F + 3 * R1, F + 4 * R1, F);
  }
  proj_k<128, 640><<<dim3(32, 2, 32), 256, 0, stream>>>(Wg1t, F, bg1, G, 128, 0);
  candpack<<<4096, 256, 0, stream>>>(G, F, 128, 64);
  if (big) {
    gemm256<<<g256, 512, 0, stream>>>(Sfb, F, F + R1, nullptr);
    gemm256<<<g256, 512, 0, stream>>>(Sbb, F, F + 3 * R1, nullptr);
    gemm256<<<g256, 512, 0, stream>>>(Sfb, F + R1, F + 2 * R1, F);
    gemm256<<<g256, 512, 0, stream>>>(Sbb, F + 3 * R1, F + 4 * R1, F);
  } else {
    gemm_s<<<dim3(32, 32), 256, 0, stream>>>(Sf, F, F + R1, nullptr);
    gemm_s<<<dim3(32, 32), 256, 0, stream>>>(Sb, F, F + 3 * R1, nullptr);
    gemm_s<<<dim3(32, 32), 256, 0, stream>>>(Sf, F + R1, F + 2 * R1, F);
    gemm_s<<<dim3(32, 32), 256, 0, stream>>>(Sb, F + 3 * R1, F + 4 * R1, F);
  }
  proj_k<128, 640><<<dim3(32, 1, 32), 256, 0, stream>>>(Wc1t, F, bc1, G, 128, 1);
  hnew_k<<<dim3(64, 32), 256, 0, stream>>>(G, HID1, F, OUT_H1);

  predictk<<<512, 256, 0, stream>>>(OUT_H1, Wp, bp, OUT);
}